// Round 8
// baseline (250.868 us; speedup 1.0000x reference)
//
#include <hip/hip_runtime.h>
#include <cstdint>

#define GNY 1024
#define GNX 2048
#define GNPTS (GNY * GNX)

namespace {
constexpr float DT = 0.1f;
constexpr float NUc = 0.01f;
constexpr float INV_DIAG = -0.375f;   // 1/DIAG, DIAG = -8/(3*dx^2) = -8/3
}

// ---- boundary-condition index maps (verified against JAX .at[].set order) ----
__device__ __forceinline__ float bc_u_at(const float* __restrict__ f, int y, int x) {
    if (y < 0 || y >= GNY || x < 0) return 1.0f;
    if (x >= GNX) x = GNX - 1;
    return f[y * GNX + x];
}
__device__ __forceinline__ float bc_v_at(const float* __restrict__ f, int y, int x) {
    if (y < 0 || y >= GNY || x < 0) return 0.0f;
    if (x >= GNX) x = GNX - 1;
    return f[y * GNX + x];
}
__device__ __forceinline__ float bc_p_at(const float* __restrict__ f, int y, int x) {
    if (x >= GNX) return 0.0f;          // right ghost = 0 (dominates corners)
    if (x < 0) x = 0;
    y = min(max(y, 0), GNY - 1);
    return f[y * GNX + x];
}

// ---- stencils (cross-correlation, m[dy][dx] = f(y+dy-1, x+dx-1)) ----
__device__ __forceinline__ float conv_x3(const float m[3][3]) {
    return ((m[0][2] - m[0][0]) + 4.0f * (m[1][2] - m[1][0]) + (m[2][2] - m[2][0])) * (1.0f / 12.0f);
}
__device__ __forceinline__ float conv_y3(const float m[3][3]) {
    return ((m[2][0] - m[0][0]) + 4.0f * (m[2][1] - m[0][1]) + (m[2][2] - m[0][2])) * (1.0f / 12.0f);
}
__device__ __forceinline__ float conv_d3(const float m[3][3]) {
    return (m[0][0] + m[0][1] + m[0][2] + m[1][0] + m[1][2] + m[2][0] + m[2][1] + m[2][2]
            - 8.0f * m[1][1]) * (1.0f / 3.0f);
}

// up-step value: a(y,x) = P(par)(y,x) - conv(bc0(P(par)))/DIAG + r/DIAG at level (H,W)
template <typename PG>
__device__ __forceinline__ float up_val(PG pget, float rval, int H, int W, int y, int x) {
    float m[3][3];
#pragma unroll
    for (int dy = 0; dy < 3; ++dy)
#pragma unroll
        for (int dx = 0; dx < 3; ++dx) {
            int yy = y + dy - 1, xx = x + dx - 1;
            m[dy][dx] = (yy >= 0 && yy < H && xx >= 0 && xx < W) ? pget(yy >> 1, xx >> 1) : 0.0f;
        }
    float conv = (m[0][0] + m[0][1] + m[0][2] + m[1][0] + m[1][2]
                  + m[2][0] + m[2][1] + m[2][2] - 8.0f * m[1][1]) * (1.0f / 3.0f);
    return m[1][1] - conv * INV_DIAG + rval * INV_DIAG;
}

// ---- FUSED front-end with bc-mapped LDS staging (round-7 verified, unchanged) ----
__global__ __launch_bounds__(256) void k_front(
        const float* __restrict__ u, const float* __restrict__ v,
        const float* __restrict__ p, const float* __restrict__ sigma,
        float* __restrict__ u2g, float* __restrict__ v2g, float* __restrict__ bg,
        float* __restrict__ r1, float* __restrict__ r2, float* __restrict__ r3,
        float* __restrict__ r4, float* __restrict__ r5) {
    __shared__ float scrF[7110];
    float* sP    = scrF;              // 38x38 stride 39 (1482), origin (y0-3,x0-3), persists
    float* sU    = scrF + 1482;       // phase A (1482)
    float* sV    = scrF + 2964;       // phase A (1482)
    float* sU2   = scrF + 1482;       // phase B overlay, 34x35 (1190), origin (y0-1,x0-1)
    float* sV2   = scrF + 2672;       // (1190)
    float* sBu   = scrF + 4446;       // 36x37 (1332), origin (y0-2,x0-2)
    float* sBv   = scrF + 5778;       // (1332, ends 7110)
    float* s0    = scrF + 4446;       // phase C overlay: 32x33 (1056)
    float* s1    = scrF + 5502;       // 16x17 (272)
    float* s2    = scrF + 5774;       // 8x9 (72)
    float* s3    = scrF + 5846;       // 4x5 (20)
    float* s4    = scrF + 5866;       // 2x3 (6)

    int t = threadIdx.x;
    int bx = blockIdx.x, by = blockIdx.y;
    int y0 = by * 32, x0 = bx * 32;
    bool edge = !(bx >= 1 && bx <= 62 && by >= 1 && by <= 30);
    bool rightcol = (bx == 63);

    if (!edge) {
        for (int i = t; i < 1444; i += 256) {
            int wy = i / 38, wx = i - wy * 38;
            int idx = (y0 - 3 + wy) * GNX + (x0 - 3 + wx);
            sP[wy * 39 + wx] = p[idx];
            sU[wy * 39 + wx] = u[idx];
            sV[wy * 39 + wx] = v[idx];
        }
    } else {
        for (int i = t; i < 1444; i += 256) {
            int wy = i / 38, wx = i - wy * 38;
            int gy = y0 - 3 + wy, gx = x0 - 3 + wx;
            sP[wy * 39 + wx] = bc_p_at(p, gy, gx);
            sU[wy * 39 + wx] = bc_u_at(u, gy, gx);
            sV[wy * 39 + wx] = bc_v_at(v, gy, gx);
        }
    }
    __syncthreads();

    // phase A: predictor on 36x36 window
    for (int i = t; i < 1296; i += 256) {
        int ay = i / 36, ax = i - ay * 36;
        int gy = y0 - 2 + ay, gx = x0 - 2 + ax;
        float un[3][3], vn[3][3], pn[3][3];
#pragma unroll
        for (int dy = 0; dy < 3; ++dy)
#pragma unroll
            for (int dx = 0; dx < 3; ++dx) {
                int li = (ay + dy) * 39 + ax + dx;
                un[dy][dx] = sU[li]; vn[dy][dx] = sV[li]; pn[dy][dx] = sP[li];
            }
        float buv, bvv;
        bool valid = !edge || (gy >= 0 && gy < GNY && gx >= 0 && gx < GNX);
        if (valid) {
            float dampv = 1.0f / (1.0f + DT * sigma[gy * GNX + gx]);
            float gxp = conv_x3(pn) * DT, gyp = conv_y3(pn) * DT;
            float uc = un[1][1], vc = vn[1][1];
            buv = (uc + 0.5f * (NUc * conv_d3(un) * DT - uc * conv_x3(un) * DT - vc * conv_y3(un) * DT) - gxp) * dampv;
            bvv = (vc + 0.5f * (NUc * conv_d3(vn) * DT - uc * conv_x3(vn) * DT - vc * conv_y3(vn) * DT) - gyp) * dampv;
        } else if (gy < 0 || gy >= GNY || gx < 0) {
            buv = 1.0f; bvv = 0.0f;
        } else {
            buv = 0.0f; bvv = 0.0f;
        }
        sBu[ay * 37 + ax] = buv;
        sBv[ay * 37 + ax] = bvv;
    }
    __syncthreads();

    // phase B: corrector on 34x34 window
    float ucA[5], vcA[5];
    {
        int np = 0;
        for (int i = t; i < 1156; i += 256, ++np) {
            int cy = i / 34, cx = i - cy * 34;
            int li = (cy + 2) * 39 + cx + 2;
            ucA[np] = sU[li]; vcA[np] = sV[li];
        }
    }
    __syncthreads();
    {
        int np = 0;
        for (int i = t; i < 1156; i += 256, ++np) {
            int cy = i / 34, cx = i - cy * 34;
            int gy = y0 - 1 + cy, gx = x0 - 1 + cx;
            float u2_ = 0.0f, v2_ = 0.0f;
            bool valid = (gy >= 0 && gy < GNY && gx >= 0 && gx < GNX);
            if (valid) {
                float bun[3][3], bvn[3][3], pn[3][3];
                if (!rightcol) {
#pragma unroll
                    for (int dy = 0; dy < 3; ++dy)
#pragma unroll
                        for (int dx = 0; dx < 3; ++dx) {
                            int li = (cy + dy) * 37 + cx + dx;
                            bun[dy][dx] = sBu[li]; bvn[dy][dx] = sBv[li];
                            pn[dy][dx] = sP[(cy + dy + 1) * 39 + cx + dx + 1];
                        }
                } else {
#pragma unroll
                    for (int dy = 0; dy < 3; ++dy)
#pragma unroll
                        for (int dx = 0; dx < 3; ++dx) {
                            int yy = gy + dy - 1, xx = gx + dx - 1;
                            pn[dy][dx] = sP[(cy + dy + 1) * 39 + cx + dx + 1];
                            if (yy < 0 || yy >= GNY || xx < 0) { bun[dy][dx] = 1.0f; bvn[dy][dx] = 0.0f; }
                            else {
                                int cxx = (xx >= GNX) ? GNX - 1 : xx;
                                int li = (cy + dy) * 37 + (cxx - (x0 - 2));
                                bun[dy][dx] = sBu[li]; bvn[dy][dx] = sBv[li];
                            }
                        }
                }
                int idx = gy * GNX + gx;
                float gxp = conv_x3(pn) * DT, gyp = conv_y3(pn) * DT;
                float dampv = 1.0f / (1.0f + DT * sigma[idx]);
                float buc = bun[1][1], bvc = bvn[1][1];
                u2_ = (ucA[np] + NUc * conv_d3(bun) * DT - buc * conv_x3(bun) * DT - bvc * conv_y3(bun) * DT - gxp) * dampv;
                v2_ = (vcA[np] + NUc * conv_d3(bvn) * DT - buc * conv_x3(bvn) * DT - bvc * conv_y3(bvn) * DT - gyp) * dampv;
                if (cy >= 1 && cy <= 32 && cx >= 1 && cx <= 32) {
                    u2g[idx] = u2_; v2g[idx] = v2_;
                }
            } else if (gy < 0 || gy >= GNY || gx < 0) {
                u2_ = 1.0f; v2_ = 0.0f;
            }
            sU2[cy * 35 + cx] = u2_;
            sV2[cy * 35 + cx] = v2_;
        }
    }
    __syncthreads();

    // phase C: b on tile + r0 = A p - b
    for (int i = t; i < 1024; i += 256) {
        int ty = i >> 5, tx = i & 31;
        int gy = y0 + ty, gx = x0 + tx;
        float un[3][3], vn[3][3], pn[3][3];
        if (!rightcol) {
#pragma unroll
            for (int dy = 0; dy < 3; ++dy)
#pragma unroll
                for (int dx = 0; dx < 3; ++dx) {
                    int li = (ty + dy) * 35 + tx + dx;
                    un[dy][dx] = sU2[li]; vn[dy][dx] = sV2[li];
                    pn[dy][dx] = sP[(ty + dy + 2) * 39 + tx + dx + 2];
                }
        } else {
#pragma unroll
            for (int dy = 0; dy < 3; ++dy)
#pragma unroll
                for (int dx = 0; dx < 3; ++dx) {
                    int yy = gy + dy - 1, xx = gx + dx - 1;
                    pn[dy][dx] = sP[(ty + dy + 2) * 39 + tx + dx + 2];
                    if (yy < 0 || yy >= GNY || xx < 0) { un[dy][dx] = 1.0f; vn[dy][dx] = 0.0f; }
                    else {
                        int cxx = (xx >= GNX) ? GNX - 1 : xx;
                        int li = (ty + dy) * 35 + (cxx - (x0 - 1));
                        un[dy][dx] = sU2[li]; vn[dy][dx] = sV2[li];
                    }
                }
        }
        float b_ = -(conv_x3(un) + conv_y3(vn)) * (1.0f / DT);
        bg[gy * GNX + gx] = b_;
        s0[ty * 33 + tx] = conv_d3(pn) - b_;
    }
    __syncthreads();

    // restriction chain r0 -> r1..r5
    { int qy = t >> 4, qx = t & 15;
      float vv = 0.25f * (s0[(2*qy)*33 + 2*qx] + s0[(2*qy)*33 + 2*qx + 1]
                        + s0[(2*qy+1)*33 + 2*qx] + s0[(2*qy+1)*33 + 2*qx + 1]);
      s1[qy*17 + qx] = vv;
      r1[(by*16 + qy)*1024 + bx*16 + qx] = vv; }
    __syncthreads();
    if (t < 64) { int qy = t >> 3, qx = t & 7;
      float vv = 0.25f * (s1[(2*qy)*17 + 2*qx] + s1[(2*qy)*17 + 2*qx + 1]
                        + s1[(2*qy+1)*17 + 2*qx] + s1[(2*qy+1)*17 + 2*qx + 1]);
      s2[qy*9 + qx] = vv;
      r2[(by*8 + qy)*512 + bx*8 + qx] = vv; }
    __syncthreads();
    if (t < 16) { int qy = t >> 2, qx = t & 3;
      float vv = 0.25f * (s2[(2*qy)*9 + 2*qx] + s2[(2*qy)*9 + 2*qx + 1]
                        + s2[(2*qy+1)*9 + 2*qx] + s2[(2*qy+1)*9 + 2*qx + 1]);
      s3[qy*5 + qx] = vv;
      r3[(by*4 + qy)*256 + bx*4 + qx] = vv; }
    __syncthreads();
    if (t < 4) { int qy = t >> 1, qx = t & 1;
      float vv = 0.25f * (s3[(2*qy)*5 + 2*qx] + s3[(2*qy)*5 + 2*qx + 1]
                        + s3[(2*qy+1)*5 + 2*qx] + s3[(2*qy+1)*5 + 2*qx + 1]);
      s4[qy*3 + qx] = vv;
      r4[(by*2 + qy)*128 + bx*2 + qx] = vv; }
    __syncthreads();
    if (t == 0)
        r5[by*64 + bx] = 0.25f * (s4[0] + s4[1] + s4[3] + s4[4]);
}

// ---- ONE fused MG iteration; p/b prefetched in an entry burst ----
// p window -> 6 VGPRs/thread, b window -> dedicated LDS (also serves resid phase).
__global__ __launch_bounds__(256) void k_mg(
        const float* __restrict__ p_src, const float* __restrict__ b,
        const float* __restrict__ r1, const float* __restrict__ r2,
        const float* __restrict__ r3, const float* __restrict__ r4,
        const float* __restrict__ r5,
        float* __restrict__ p_dst,
        float* __restrict__ o1, float* __restrict__ o2, float* __restrict__ o3,
        float* __restrict__ o4, float* __restrict__ o5,
        const float* __restrict__ sigma, float* __restrict__ u_io,
        float* __restrict__ v_io, int last) {
    __shared__ float scr[3948];
    __shared__ float w6v[9], w5v[9], w4v[16], w3v[36], w2v[100], w1v[324];
    __shared__ float gB[1190];   // 34x35 bc-clamped b window, persists whole kernel
    float* s5  = scr;            // 32x64 = 2048
    float* s6  = scr + 2048;     // 16x32 = 512
    float* s7  = scr + 2560;     // 8x16  = 128
    float* s8  = scr + 2688;     // 4x8   = 32
    float* s9  = scr + 2720;     // 2x4   = 8
    float* s10 = scr + 2728;     // 1x2   = 2
    float* a9  = scr + 2730;     // 8
    float* a8  = scr + 2738;     // 32
    float* a7  = scr + 2770;     // 128
    float* sPp = scr;            // 36x36, stride 37 = 1332 (bc_p-mapped p')
    float* sPn = scr + 1332;     // 34x34, stride 35 = 1190 (bc_p-mapped p_next)
    float* s0  = scr + 2522;     // 32x33 = 1056
    float* s1  = scr + 3578;     // 16x17 = 272
    float* s2  = scr + 3850;     // 8x9   = 72
    float* s3  = scr + 3922;     // 4x5   = 20
    float* s4  = scr + 3942;     // 2x3   = 6

    int t = threadIdx.x;
    int bx = blockIdx.x, by = blockIdx.y;
    int y0 = by * 32, x0 = bx * 32;
    int w1ylo = 16*by - 1, w1xlo = 16*bx - 1;

    // ---- entry burst: ALL big global reads issued back-to-back ----
    float r5R[8];
#pragma unroll
    for (int k = 0; k < 8; ++k) r5R[k] = r5[t + 256 * k];
    float pR[6];
#pragma unroll
    for (int k = 0; k < 6; ++k) {
        int i = t + 256 * k;
        pR[k] = 0.0f;
        if (i < 1296) {
            int wy = i / 36, wx = i - wy * 36;
            int yy = y0 - 2 + wy, xx = x0 - 2 + wx;
            if (xx < GNX) {
                int cy = min(max(yy, 0), GNY - 1), cx = xx < 0 ? 0 : xx;
                pR[k] = p_src[cy * GNX + cx];
            }
        }
    }
#pragma unroll
    for (int k = 0; k < 5; ++k) {
        int i = t + 256 * k;
        if (i < 1156) {
            int wy = i / 34, wx = i - wy * 34;
            int yy = y0 - 1 + wy, xx = x0 - 1 + wx;
            float v = 0.0f;
            if (xx < GNX) {
                int cy = min(max(yy, 0), GNY - 1), cx = xx < 0 ? 0 : xx;
                v = b[cy * GNX + cx];
            }
            gB[wy * 35 + wx] = v;
        }
    }
#pragma unroll
    for (int k = 0; k < 8; ++k) s5[t + 256 * k] = r5R[k];
    __syncthreads();

    // phase 1: full restriction r5 -> r10, full up a10->a7
    for (int i = t; i < 512; i += 256) {
        int y = i >> 5, x = i & 31;
        s6[i] = 0.25f * (s5[(2*y)*64 + 2*x] + s5[(2*y)*64 + 2*x + 1]
                       + s5[(2*y+1)*64 + 2*x] + s5[(2*y+1)*64 + 2*x + 1]);
    }
    __syncthreads();
    if (t < 128) { int y = t >> 4, x = t & 15;
        s7[t] = 0.25f * (s6[(2*y)*32 + 2*x] + s6[(2*y)*32 + 2*x + 1]
                       + s6[(2*y+1)*32 + 2*x] + s6[(2*y+1)*32 + 2*x + 1]); }
    __syncthreads();
    if (t < 32) { int y = t >> 3, x = t & 7;
        s8[t] = 0.25f * (s7[(2*y)*16 + 2*x] + s7[(2*y)*16 + 2*x + 1]
                       + s7[(2*y+1)*16 + 2*x] + s7[(2*y+1)*16 + 2*x + 1]); }
    __syncthreads();
    if (t < 8) { int y = t >> 2, x = t & 3;
        s9[t] = 0.25f * (s8[(2*y)*8 + 2*x] + s8[(2*y)*8 + 2*x + 1]
                       + s8[(2*y+1)*8 + 2*x] + s8[(2*y+1)*8 + 2*x + 1]); }
    __syncthreads();
    if (t < 2)
        s10[t] = 0.25f * (s9[2*t] + s9[2*t + 1] + s9[4 + 2*t] + s9[4 + 2*t + 1]);
    __syncthreads();
    if (t < 8) { int y = t >> 2, x = t & 3;
        a9[t] = up_val([&](int py, int px) { return s10[py*2 + px] * INV_DIAG; },
                       s9[t], 2, 4, y, x); }
    __syncthreads();
    if (t < 32) { int y = t >> 3, x = t & 7;
        a8[t] = up_val([&](int py, int px) { return a9[py*4 + px]; },
                       s8[t], 4, 8, y, x); }
    __syncthreads();
    if (t < 128) { int y = t >> 4, x = t & 15;
        a7[t] = up_val([&](int py, int px) { return a8[py*8 + px]; },
                       s7[t], 8, 16, y, x); }
    __syncthreads();

    // phase 2: windowed up-sweep a6..a1
    int w6ylo = (by - 2) >> 1, w6xlo = (bx - 2) >> 1;
    int w5ylo = by - 1,        w5xlo = bx - 1;
    int w4ylo = 2*by - 1,      w4xlo = 2*bx - 1;
    int w3ylo = 4*by - 1,      w3xlo = 4*bx - 1;
    int w2ylo = 8*by - 1,      w2xlo = 8*bx - 1;

    if (t < 9) { int gy = w6ylo + t/3, gx = w6xlo + t%3;
        w6v[t] = (gy >= 0 && gy < 16 && gx >= 0 && gx < 32)
            ? up_val([&](int py, int px) { return a7[py*16 + px]; },
                     s6[gy*32 + gx], 16, 32, gy, gx) : 0.0f; }
    __syncthreads();
    if (t < 9) { int gy = w5ylo + t/3, gx = w5xlo + t%3;
        w5v[t] = (gy >= 0 && gy < 32 && gx >= 0 && gx < 64)
            ? up_val([&](int py, int px) { return w6v[(py - w6ylo)*3 + (px - w6xlo)]; },
                     s5[gy*64 + gx], 32, 64, gy, gx) : 0.0f; }
    __syncthreads();
    if (t < 16) { int gy = w4ylo + t/4, gx = w4xlo + t%4;
        w4v[t] = (gy >= 0 && gy < 64 && gx >= 0 && gx < 128)
            ? up_val([&](int py, int px) { return w5v[(py - w5ylo)*3 + (px - w5xlo)]; },
                     r4[gy*128 + gx], 64, 128, gy, gx) : 0.0f; }
    __syncthreads();
    if (t < 36) { int gy = w3ylo + t/6, gx = w3xlo + t%6;
        w3v[t] = (gy >= 0 && gy < 128 && gx >= 0 && gx < 256)
            ? up_val([&](int py, int px) { return w4v[(py - w4ylo)*4 + (px - w4xlo)]; },
                     r3[gy*256 + gx], 128, 256, gy, gx) : 0.0f; }
    __syncthreads();
    if (t < 100) { int gy = w2ylo + t/10, gx = w2xlo + t%10;
        w2v[t] = (gy >= 0 && gy < 256 && gx >= 0 && gx < 512)
            ? up_val([&](int py, int px) { return w3v[(py - w3ylo)*6 + (px - w3xlo)]; },
                     r2[gy*512 + gx], 256, 512, gy, gx) : 0.0f; }
    __syncthreads();
    for (int i = t; i < 324; i += 256) { int gy = w1ylo + i/18, gx = w1xlo + i%18;
        w1v[i] = (gy >= 0 && gy < 512 && gx >= 0 && gx < 1024)
            ? up_val([&](int py, int px) { return w2v[(py - w2ylo)*10 + (px - w2xlo)]; },
                     r1[gy*1024 + gx], 512, 1024, gy, gx) : 0.0f; }
    __syncthreads();

    // phase 3a: sPp = bc_p-mapped p' on 36x36 window (p from registers)
#pragma unroll
    for (int k = 0; k < 6; ++k) {
        int i = t + 256 * k;
        if (i < 1296) {
            int wy = i / 36, wx = i - wy * 36;
            int yy = y0 - 2 + wy, xx = x0 - 2 + wx;
            float v = 0.0f;
            if (xx < GNX) {
                int cy = min(max(yy, 0), GNY - 1), cx = xx < 0 ? 0 : xx;
                v = pR[k] - w1v[((cy >> 1) - w1ylo)*18 + ((cx >> 1) - w1xlo)];
            }
            sPp[wy*37 + wx] = v;
        }
    }
    __syncthreads();
    // phase 3b: sPn = bc_p-mapped p_next on 34x34 window (clamp-then-stencil; b from LDS)
    for (int i = t; i < 1156; i += 256) {
        int wy = i / 34, wx = i - wy * 34;
        int yy = y0 - 1 + wy, xx = x0 - 1 + wx;
        float v = 0.0f;
        if (xx < GNX) {
            int cy = min(max(yy, 0), GNY - 1);
            int cx = xx < 0 ? 0 : xx;
            int rb = cy - y0 + 2, cb = cx - x0 + 2;   // sPp coords of clamped center
            float m[3][3];
#pragma unroll
            for (int dy = 0; dy < 3; ++dy)
#pragma unroll
                for (int dx = 0; dx < 3; ++dx)
                    m[dy][dx] = sPp[(rb + dy - 1)*37 + (cb + dx - 1)];
            float conv = (m[0][0] + m[0][1] + m[0][2] + m[1][0] + m[1][2]
                          + m[2][0] + m[2][1] + m[2][2] - 8.0f*m[1][1]) * (1.0f / 3.0f);
            v = m[1][1] - conv * INV_DIAG + gB[wy*35 + wx] * INV_DIAG;
        }
        sPn[wy*35 + wx] = v;
    }
    __syncthreads();
    // write own p tile
    for (int i = t; i < 1024; i += 256) {
        int ty = i >> 5, tx = i & 31;
        p_dst[(y0 + ty)*GNX + x0 + tx] = sPn[(ty + 1)*35 + (tx + 1)];
    }

    if (!last) {
        // next-iteration residual on tile + restriction (b from LDS)
        for (int i = t; i < 1024; i += 256) {
            int ty = i >> 5, tx = i & 31;
            float m[3][3];
#pragma unroll
            for (int dy = 0; dy < 3; ++dy)
#pragma unroll
                for (int dx = 0; dx < 3; ++dx)
                    m[dy][dx] = sPn[(ty + dy)*35 + (tx + dx)];
            s0[ty*33 + tx] = conv_d3(m) - gB[(ty + 1)*35 + (tx + 1)];
        }
        __syncthreads();
        { int qy = t >> 4, qx = t & 15;
          float v = 0.25f * (s0[(2*qy)*33 + 2*qx] + s0[(2*qy)*33 + 2*qx + 1]
                           + s0[(2*qy+1)*33 + 2*qx] + s0[(2*qy+1)*33 + 2*qx + 1]);
          s1[qy*17 + qx] = v;
          o1[(by*16 + qy)*1024 + bx*16 + qx] = v; }
        __syncthreads();
        if (t < 64) { int qy = t >> 3, qx = t & 7;
          float v = 0.25f * (s1[(2*qy)*17 + 2*qx] + s1[(2*qy)*17 + 2*qx + 1]
                           + s1[(2*qy+1)*17 + 2*qx] + s1[(2*qy+1)*17 + 2*qx + 1]);
          s2[qy*9 + qx] = v;
          o2[(by*8 + qy)*512 + bx*8 + qx] = v; }
        __syncthreads();
        if (t < 16) { int qy = t >> 2, qx = t & 3;
          float v = 0.25f * (s2[(2*qy)*9 + 2*qx] + s2[(2*qy)*9 + 2*qx + 1]
                           + s2[(2*qy+1)*9 + 2*qx] + s2[(2*qy+1)*9 + 2*qx + 1]);
          s3[qy*5 + qx] = v;
          o3[(by*4 + qy)*256 + bx*4 + qx] = v; }
        __syncthreads();
        if (t < 4) { int qy = t >> 1, qx = t & 1;
          float v = 0.25f * (s3[(2*qy)*5 + 2*qx] + s3[(2*qy)*5 + 2*qx + 1]
                           + s3[(2*qy+1)*5 + 2*qx] + s3[(2*qy+1)*5 + 2*qx + 1]);
          s4[qy*3 + qx] = v;
          o4[(by*2 + qy)*128 + bx*2 + qx] = v; }
        __syncthreads();
        if (t == 0)
            o5[by*64 + bx] = 0.25f * (s4[0] + s4[1] + s4[3] + s4[4]);
    } else {
        // fused projection
        for (int i = t; i < 1024; i += 256) {
            int ty = i >> 5, tx = i & 31;
            float m[3][3];
#pragma unroll
            for (int dy = 0; dy < 3; ++dy)
#pragma unroll
                for (int dx = 0; dx < 3; ++dx)
                    m[dy][dx] = sPn[(ty + dy)*35 + (tx + dx)];
            int idx = (y0 + ty)*GNX + x0 + tx;
            float damp = 1.0f / (1.0f + DT * sigma[idx]);
            u_io[idx] = (u_io[idx] - conv_x3(m) * DT) * damp;
            v_io[idx] = (v_io[idx] - conv_y3(m) * DT) * damp;
        }
    }
}

extern "C" void kernel_launch(void* const* d_in, const int* in_sizes, int n_in,
                              void* d_out, int out_size, void* d_ws, size_t ws_size,
                              hipStream_t stream) {
    (void)in_sizes; (void)n_in; (void)out_size; (void)ws_size;
    const float* u_in  = (const float*)d_in[0];
    const float* v_in  = (const float*)d_in[1];
    const float* p_in  = (const float*)d_in[2];
    const float* sigma = (const float*)d_in[3];

    float* out_u = (float*)d_out;
    float* out_v = out_u + GNPTS;
    float* out_p = out_u + 2 * (size_t)GNPTS;

    float* ws   = (float*)d_ws;
    float* b    = ws;
    float* p_ws = b + (size_t)GNPTS;
    float* base = p_ws + (size_t)GNPTS;
    float* A_[5], * B_[5];
    size_t lsz[5] = {524288, 131072, 32768, 8192, 2048};
    float* cur = base;
    for (int l = 0; l < 5; ++l) { A_[l] = cur; cur += lsz[l]; }
    for (int l = 0; l < 5; ++l) { B_[l] = cur; cur += lsz[l]; }

    dim3 grdT(GNX / 32, GNY / 32), blkT(256);

    k_front<<<grdT, blkT, 0, stream>>>(u_in, v_in, p_in, sigma,
                                       out_u, out_v, b,
                                       A_[0], A_[1], A_[2], A_[3], A_[4]);

    const float* p_cur = p_in;
    float* p_bufs[2] = { out_p, p_ws };   // it0->out_p, it1->p_ws, ..., it4->out_p
    for (int it = 0; it < 5; ++it) {
        float** rp = (it % 2 == 0) ? A_ : B_;
        float** wp = (it % 2 == 0) ? B_ : A_;
        float* p_next = p_bufs[it % 2];
        int last = (it == 4) ? 1 : 0;
        k_mg<<<grdT, blkT, 0, stream>>>(p_cur, b,
                                        rp[0], rp[1], rp[2], rp[3], rp[4],
                                        p_next,
                                        wp[0], wp[1], wp[2], wp[3], wp[4],
                                        sigma, out_u, out_v, last);
        p_cur = p_next;
    }
}

// Round 9
// 220.115 us; speedup vs baseline: 1.1397x; 1.1397x over previous
//
#include <hip/hip_runtime.h>
#include <cstdint>

#define GNY 1024
#define GNX 2048
#define GNPTS (GNY * GNX)

namespace {
constexpr float DT = 0.1f;
constexpr float NUc = 0.01f;
constexpr float INV_DIAG = -0.375f;   // 1/DIAG, DIAG = -8/(3*dx^2) = -8/3
}

// ---- boundary-condition index maps (verified against JAX .at[].set order) ----
__device__ __forceinline__ float bc_u_at(const float* __restrict__ f, int y, int x) {
    if (y < 0 || y >= GNY || x < 0) return 1.0f;
    if (x >= GNX) x = GNX - 1;
    return f[y * GNX + x];
}
__device__ __forceinline__ float bc_v_at(const float* __restrict__ f, int y, int x) {
    if (y < 0 || y >= GNY || x < 0) return 0.0f;
    if (x >= GNX) x = GNX - 1;
    return f[y * GNX + x];
}
__device__ __forceinline__ float bc_p_at(const float* __restrict__ f, int y, int x) {
    if (x >= GNX) return 0.0f;          // right ghost = 0 (dominates corners)
    if (x < 0) x = 0;
    y = min(max(y, 0), GNY - 1);
    return f[y * GNX + x];
}

// ---- stencils (cross-correlation, m[dy][dx] = f(y+dy-1, x+dx-1)) ----
__device__ __forceinline__ float conv_x3(const float m[3][3]) {
    return ((m[0][2] - m[0][0]) + 4.0f * (m[1][2] - m[1][0]) + (m[2][2] - m[2][0])) * (1.0f / 12.0f);
}
__device__ __forceinline__ float conv_y3(const float m[3][3]) {
    return ((m[2][0] - m[0][0]) + 4.0f * (m[2][1] - m[0][1]) + (m[2][2] - m[0][2])) * (1.0f / 12.0f);
}
__device__ __forceinline__ float conv_d3(const float m[3][3]) {
    return (m[0][0] + m[0][1] + m[0][2] + m[1][0] + m[1][2] + m[2][0] + m[2][1] + m[2][2]
            - 8.0f * m[1][1]) * (1.0f / 3.0f);
}

// up-step value: a(y,x) = P(par)(y,x) - conv(bc0(P(par)))/DIAG + r/DIAG at level (H,W)
template <typename PG>
__device__ __forceinline__ float up_val(PG pget, float rval, int H, int W, int y, int x) {
    float m[3][3];
#pragma unroll
    for (int dy = 0; dy < 3; ++dy)
#pragma unroll
        for (int dx = 0; dx < 3; ++dx) {
            int yy = y + dy - 1, xx = x + dx - 1;
            m[dy][dx] = (yy >= 0 && yy < H && xx >= 0 && xx < W) ? pget(yy >> 1, xx >> 1) : 0.0f;
        }
    float conv = (m[0][0] + m[0][1] + m[0][2] + m[1][0] + m[1][2]
                  + m[2][0] + m[2][1] + m[2][2] - 8.0f * m[1][1]) * (1.0f / 3.0f);
    return m[1][1] - conv * INV_DIAG + rval * INV_DIAG;
}

// ---- FUSED front-end with bc-mapped LDS staging (round-7 verified, unchanged) ----
__global__ __launch_bounds__(256) void k_front(
        const float* __restrict__ u, const float* __restrict__ v,
        const float* __restrict__ p, const float* __restrict__ sigma,
        float* __restrict__ u2g, float* __restrict__ v2g, float* __restrict__ bg,
        float* __restrict__ r1, float* __restrict__ r2, float* __restrict__ r3,
        float* __restrict__ r4, float* __restrict__ r5) {
    __shared__ float scrF[7110];
    float* sP    = scrF;              // 38x38 stride 39 (1482), origin (y0-3,x0-3), persists
    float* sU    = scrF + 1482;       // phase A (1482)
    float* sV    = scrF + 2964;       // phase A (1482)
    float* sU2   = scrF + 1482;       // phase B overlay, 34x35 (1190), origin (y0-1,x0-1)
    float* sV2   = scrF + 2672;       // (1190)
    float* sBu   = scrF + 4446;       // 36x37 (1332), origin (y0-2,x0-2)
    float* sBv   = scrF + 5778;       // (1332, ends 7110)
    float* s0    = scrF + 4446;       // phase C overlay: 32x33 (1056)
    float* s1    = scrF + 5502;       // 16x17 (272)
    float* s2    = scrF + 5774;       // 8x9 (72)
    float* s3    = scrF + 5846;       // 4x5 (20)
    float* s4    = scrF + 5866;       // 2x3 (6)

    int t = threadIdx.x;
    int bx = blockIdx.x, by = blockIdx.y;
    int y0 = by * 32, x0 = bx * 32;
    bool edge = !(bx >= 1 && bx <= 62 && by >= 1 && by <= 30);
    bool rightcol = (bx == 63);

    if (!edge) {
        for (int i = t; i < 1444; i += 256) {
            int wy = i / 38, wx = i - wy * 38;
            int idx = (y0 - 3 + wy) * GNX + (x0 - 3 + wx);
            sP[wy * 39 + wx] = p[idx];
            sU[wy * 39 + wx] = u[idx];
            sV[wy * 39 + wx] = v[idx];
        }
    } else {
        for (int i = t; i < 1444; i += 256) {
            int wy = i / 38, wx = i - wy * 38;
            int gy = y0 - 3 + wy, gx = x0 - 3 + wx;
            sP[wy * 39 + wx] = bc_p_at(p, gy, gx);
            sU[wy * 39 + wx] = bc_u_at(u, gy, gx);
            sV[wy * 39 + wx] = bc_v_at(v, gy, gx);
        }
    }
    __syncthreads();

    // phase A: predictor on 36x36 window
    for (int i = t; i < 1296; i += 256) {
        int ay = i / 36, ax = i - ay * 36;
        int gy = y0 - 2 + ay, gx = x0 - 2 + ax;
        float un[3][3], vn[3][3], pn[3][3];
#pragma unroll
        for (int dy = 0; dy < 3; ++dy)
#pragma unroll
            for (int dx = 0; dx < 3; ++dx) {
                int li = (ay + dy) * 39 + ax + dx;
                un[dy][dx] = sU[li]; vn[dy][dx] = sV[li]; pn[dy][dx] = sP[li];
            }
        float buv, bvv;
        bool valid = !edge || (gy >= 0 && gy < GNY && gx >= 0 && gx < GNX);
        if (valid) {
            float dampv = 1.0f / (1.0f + DT * sigma[gy * GNX + gx]);
            float gxp = conv_x3(pn) * DT, gyp = conv_y3(pn) * DT;
            float uc = un[1][1], vc = vn[1][1];
            buv = (uc + 0.5f * (NUc * conv_d3(un) * DT - uc * conv_x3(un) * DT - vc * conv_y3(un) * DT) - gxp) * dampv;
            bvv = (vc + 0.5f * (NUc * conv_d3(vn) * DT - uc * conv_x3(vn) * DT - vc * conv_y3(vn) * DT) - gyp) * dampv;
        } else if (gy < 0 || gy >= GNY || gx < 0) {
            buv = 1.0f; bvv = 0.0f;
        } else {
            buv = 0.0f; bvv = 0.0f;
        }
        sBu[ay * 37 + ax] = buv;
        sBv[ay * 37 + ax] = bvv;
    }
    __syncthreads();

    // phase B: corrector on 34x34 window
    float ucA[5], vcA[5];
    {
        int np = 0;
        for (int i = t; i < 1156; i += 256, ++np) {
            int cy = i / 34, cx = i - cy * 34;
            int li = (cy + 2) * 39 + cx + 2;
            ucA[np] = sU[li]; vcA[np] = sV[li];
        }
    }
    __syncthreads();
    {
        int np = 0;
        for (int i = t; i < 1156; i += 256, ++np) {
            int cy = i / 34, cx = i - cy * 34;
            int gy = y0 - 1 + cy, gx = x0 - 1 + cx;
            float u2_ = 0.0f, v2_ = 0.0f;
            bool valid = (gy >= 0 && gy < GNY && gx >= 0 && gx < GNX);
            if (valid) {
                float bun[3][3], bvn[3][3], pn[3][3];
                if (!rightcol) {
#pragma unroll
                    for (int dy = 0; dy < 3; ++dy)
#pragma unroll
                        for (int dx = 0; dx < 3; ++dx) {
                            int li = (cy + dy) * 37 + cx + dx;
                            bun[dy][dx] = sBu[li]; bvn[dy][dx] = sBv[li];
                            pn[dy][dx] = sP[(cy + dy + 1) * 39 + cx + dx + 1];
                        }
                } else {
#pragma unroll
                    for (int dy = 0; dy < 3; ++dy)
#pragma unroll
                        for (int dx = 0; dx < 3; ++dx) {
                            int yy = gy + dy - 1, xx = gx + dx - 1;
                            pn[dy][dx] = sP[(cy + dy + 1) * 39 + cx + dx + 1];
                            if (yy < 0 || yy >= GNY || xx < 0) { bun[dy][dx] = 1.0f; bvn[dy][dx] = 0.0f; }
                            else {
                                int cxx = (xx >= GNX) ? GNX - 1 : xx;
                                int li = (cy + dy) * 37 + (cxx - (x0 - 2));
                                bun[dy][dx] = sBu[li]; bvn[dy][dx] = sBv[li];
                            }
                        }
                }
                int idx = gy * GNX + gx;
                float gxp = conv_x3(pn) * DT, gyp = conv_y3(pn) * DT;
                float dampv = 1.0f / (1.0f + DT * sigma[idx]);
                float buc = bun[1][1], bvc = bvn[1][1];
                u2_ = (ucA[np] + NUc * conv_d3(bun) * DT - buc * conv_x3(bun) * DT - bvc * conv_y3(bun) * DT - gxp) * dampv;
                v2_ = (vcA[np] + NUc * conv_d3(bvn) * DT - buc * conv_x3(bvn) * DT - bvc * conv_y3(bvn) * DT - gyp) * dampv;
                if (cy >= 1 && cy <= 32 && cx >= 1 && cx <= 32) {
                    u2g[idx] = u2_; v2g[idx] = v2_;
                }
            } else if (gy < 0 || gy >= GNY || gx < 0) {
                u2_ = 1.0f; v2_ = 0.0f;
            }
            sU2[cy * 35 + cx] = u2_;
            sV2[cy * 35 + cx] = v2_;
        }
    }
    __syncthreads();

    // phase C: b on tile + r0 = A p - b
    for (int i = t; i < 1024; i += 256) {
        int ty = i >> 5, tx = i & 31;
        int gy = y0 + ty, gx = x0 + tx;
        float un[3][3], vn[3][3], pn[3][3];
        if (!rightcol) {
#pragma unroll
            for (int dy = 0; dy < 3; ++dy)
#pragma unroll
                for (int dx = 0; dx < 3; ++dx) {
                    int li = (ty + dy) * 35 + tx + dx;
                    un[dy][dx] = sU2[li]; vn[dy][dx] = sV2[li];
                    pn[dy][dx] = sP[(ty + dy + 2) * 39 + tx + dx + 2];
                }
        } else {
#pragma unroll
            for (int dy = 0; dy < 3; ++dy)
#pragma unroll
                for (int dx = 0; dx < 3; ++dx) {
                    int yy = gy + dy - 1, xx = gx + dx - 1;
                    pn[dy][dx] = sP[(ty + dy + 2) * 39 + tx + dx + 2];
                    if (yy < 0 || yy >= GNY || xx < 0) { un[dy][dx] = 1.0f; vn[dy][dx] = 0.0f; }
                    else {
                        int cxx = (xx >= GNX) ? GNX - 1 : xx;
                        int li = (ty + dy) * 35 + (cxx - (x0 - 1));
                        un[dy][dx] = sU2[li]; vn[dy][dx] = sV2[li];
                    }
                }
        }
        float b_ = -(conv_x3(un) + conv_y3(vn)) * (1.0f / DT);
        bg[gy * GNX + gx] = b_;
        s0[ty * 33 + tx] = conv_d3(pn) - b_;
    }
    __syncthreads();

    // restriction chain r0 -> r1..r5
    { int qy = t >> 4, qx = t & 15;
      float vv = 0.25f * (s0[(2*qy)*33 + 2*qx] + s0[(2*qy)*33 + 2*qx + 1]
                        + s0[(2*qy+1)*33 + 2*qx] + s0[(2*qy+1)*33 + 2*qx + 1]);
      s1[qy*17 + qx] = vv;
      r1[(by*16 + qy)*1024 + bx*16 + qx] = vv; }
    __syncthreads();
    if (t < 64) { int qy = t >> 3, qx = t & 7;
      float vv = 0.25f * (s1[(2*qy)*17 + 2*qx] + s1[(2*qy)*17 + 2*qx + 1]
                        + s1[(2*qy+1)*17 + 2*qx] + s1[(2*qy+1)*17 + 2*qx + 1]);
      s2[qy*9 + qx] = vv;
      r2[(by*8 + qy)*512 + bx*8 + qx] = vv; }
    __syncthreads();
    if (t < 16) { int qy = t >> 2, qx = t & 3;
      float vv = 0.25f * (s2[(2*qy)*9 + 2*qx] + s2[(2*qy)*9 + 2*qx + 1]
                        + s2[(2*qy+1)*9 + 2*qx] + s2[(2*qy+1)*9 + 2*qx + 1]);
      s3[qy*5 + qx] = vv;
      r3[(by*4 + qy)*256 + bx*4 + qx] = vv; }
    __syncthreads();
    if (t < 4) { int qy = t >> 1, qx = t & 1;
      float vv = 0.25f * (s3[(2*qy)*5 + 2*qx] + s3[(2*qy)*5 + 2*qx + 1]
                        + s3[(2*qy+1)*5 + 2*qx] + s3[(2*qy+1)*5 + 2*qx + 1]);
      s4[qy*3 + qx] = vv;
      r4[(by*2 + qy)*128 + bx*2 + qx] = vv; }
    __syncthreads();
    if (t == 0)
        r5[by*64 + bx] = 0.25f * (s4[0] + s4[1] + s4[3] + s4[4]);
}

// ---- ONE fused MG iteration; wave-specialized coarse solve ----
// Wave 0 computes the ENTIRE coarse pyramid (r5->r10->a7, windowed w6..w3)
// solo in LDS with no block barriers (in-wave lgkm ordering); waves 1-3
// concurrently stage the p window into registers and the b window into LDS.
__global__ __launch_bounds__(256) void k_mg(
        const float* __restrict__ p_src, const float* __restrict__ b,
        const float* __restrict__ r1, const float* __restrict__ r2,
        const float* __restrict__ r3, const float* __restrict__ r4,
        const float* __restrict__ r5,
        float* __restrict__ p_dst,
        float* __restrict__ o1, float* __restrict__ o2, float* __restrict__ o3,
        float* __restrict__ o4, float* __restrict__ o5,
        const float* __restrict__ sigma, float* __restrict__ u_io,
        float* __restrict__ v_io, int last) {
    __shared__ float A[3392];
    __shared__ float gB[1190];   // 34x35 bc-clamped b window (waves 1-3 stage it)
    // wave-0 coarse chain region (dead after w3):
    float* s5  = A;              // 32x64 = 2048
    float* s6  = A + 2048;       // 16x32 = 512
    float* s7  = A + 2560;       // 8x16  = 128
    float* s8  = A + 2688;       // 4x8   = 32
    float* s9  = A + 2720;       // 2x4   = 8
    float* s10 = A + 2728;       // 1x2   = 2
    float* a9  = A + 2730;       // 8
    float* a8  = A + 2738;       // 32
    float* a7  = A + 2770;       // 128 (ends 2898)
    float* w6v = A + 2898;       // 9
    float* w5v = A + 2907;       // 9
    float* w4v = A + 2916;       // 16
    float* w3v = A + 2932;       // 36
    float* w2v = A + 2968;       // 100
    float* w1v = A + 3068;       // 324 (ends 3392)
    // overlays (after coarse chain retires):
    float* sPp = A;              // 36x36, stride 37 = 1332
    float* sPn = A + 1332;       // 34x34, stride 35 = 1190 (ends 2522)
    float* s0  = A;              // 32x33 = 1056 (after sPp dead)
    float* s1  = A + 1056;       // 272 (ends 1328 < 1332, sPn safe)
    float* s2  = A + 2560;       // 72  (old s7 region, dead)
    float* s3  = A + 2632;       // 20
    float* s4  = A + 2652;       // 6

    int t = threadIdx.x;
    int bx = blockIdx.x, by = blockIdx.y;
    int y0 = by * 32, x0 = bx * 32;
    int w1ylo = 16*by - 1, w1xlo = 16*bx - 1;

    float pR[7];   // waves 1-3: p window values (7 per lane, 192 lanes)

    if (t < 64) {
        // ======== wave 0: solo coarse solve, zero block barriers ========
        int l = t;
#pragma unroll
        for (int k = 0; k < 32; ++k) s5[l + 64*k] = r5[l + 64*k];
        __builtin_amdgcn_wave_barrier();
        for (int i = l; i < 512; i += 64) {
            int y = i >> 5, x = i & 31;
            s6[i] = 0.25f * (s5[(2*y)*64 + 2*x] + s5[(2*y)*64 + 2*x + 1]
                           + s5[(2*y+1)*64 + 2*x] + s5[(2*y+1)*64 + 2*x + 1]);
        }
        __builtin_amdgcn_wave_barrier();
        for (int i = l; i < 128; i += 64) {
            int y = i >> 4, x = i & 15;
            s7[i] = 0.25f * (s6[(2*y)*32 + 2*x] + s6[(2*y)*32 + 2*x + 1]
                           + s6[(2*y+1)*32 + 2*x] + s6[(2*y+1)*32 + 2*x + 1]);
        }
        __builtin_amdgcn_wave_barrier();
        if (l < 32) { int y = l >> 3, x = l & 7;
            s8[l] = 0.25f * (s7[(2*y)*16 + 2*x] + s7[(2*y)*16 + 2*x + 1]
                           + s7[(2*y+1)*16 + 2*x] + s7[(2*y+1)*16 + 2*x + 1]); }
        __builtin_amdgcn_wave_barrier();
        if (l < 8) { int y = l >> 2, x = l & 3;
            s9[l] = 0.25f * (s8[(2*y)*8 + 2*x] + s8[(2*y)*8 + 2*x + 1]
                           + s8[(2*y+1)*8 + 2*x] + s8[(2*y+1)*8 + 2*x + 1]); }
        __builtin_amdgcn_wave_barrier();
        if (l < 2)
            s10[l] = 0.25f * (s9[2*l] + s9[2*l + 1] + s9[4 + 2*l] + s9[4 + 2*l + 1]);
        __builtin_amdgcn_wave_barrier();
        if (l < 8) { int y = l >> 2, x = l & 3;
            a9[l] = up_val([&](int py, int px) { return s10[py*2 + px] * INV_DIAG; },
                           s9[l], 2, 4, y, x); }
        __builtin_amdgcn_wave_barrier();
        if (l < 32) { int y = l >> 3, x = l & 7;
            a8[l] = up_val([&](int py, int px) { return a9[py*4 + px]; },
                           s8[l], 4, 8, y, x); }
        __builtin_amdgcn_wave_barrier();
        for (int i = l; i < 128; i += 64) { int y = i >> 4, x = i & 15;
            a7[i] = up_val([&](int py, int px) { return a8[py*8 + px]; },
                           s7[i], 8, 16, y, x); }
        __builtin_amdgcn_wave_barrier();
        int w6ylo = (by - 2) >> 1, w6xlo = (bx - 2) >> 1;
        if (l < 9) { int gy = w6ylo + l/3, gx = w6xlo + l%3;
            w6v[l] = (gy >= 0 && gy < 16 && gx >= 0 && gx < 32)
                ? up_val([&](int py, int px) { return a7[py*16 + px]; },
                         s6[gy*32 + gx], 16, 32, gy, gx) : 0.0f; }
        __builtin_amdgcn_wave_barrier();
        int w5ylo = by - 1, w5xlo = bx - 1;
        if (l < 9) { int gy = w5ylo + l/3, gx = w5xlo + l%3;
            w5v[l] = (gy >= 0 && gy < 32 && gx >= 0 && gx < 64)
                ? up_val([&](int py, int px) { return w6v[(py - w6ylo)*3 + (px - w6xlo)]; },
                         s5[gy*64 + gx], 32, 64, gy, gx) : 0.0f; }
        __builtin_amdgcn_wave_barrier();
        int w4ylo = 2*by - 1, w4xlo = 2*bx - 1;
        if (l < 16) { int gy = w4ylo + l/4, gx = w4xlo + l%4;
            w4v[l] = (gy >= 0 && gy < 64 && gx >= 0 && gx < 128)
                ? up_val([&](int py, int px) { return w5v[(py - w5ylo)*3 + (px - w5xlo)]; },
                         r4[gy*128 + gx], 64, 128, gy, gx) : 0.0f; }
        __builtin_amdgcn_wave_barrier();
        int w3ylo = 4*by - 1, w3xlo = 4*bx - 1;
        if (l < 36) { int gy = w3ylo + l/6, gx = w3xlo + l%6;
            w3v[l] = (gy >= 0 && gy < 128 && gx >= 0 && gx < 256)
                ? up_val([&](int py, int px) { return w4v[(py - w4ylo)*4 + (px - w4xlo)]; },
                         r3[gy*256 + gx], 128, 256, gy, gx) : 0.0f; }
    } else {
        // ======== waves 1-3: stage p window (regs) and b window (LDS) ========
        int j = t - 64;
#pragma unroll
        for (int k = 0; k < 7; ++k) {
            int i = j + 192 * k;
            pR[k] = 0.0f;
            if (i < 1296) {
                int wy = i / 36, wx = i - wy * 36;
                int yy = y0 - 2 + wy, xx = x0 - 2 + wx;
                if (xx < GNX) {
                    int cy = min(max(yy, 0), GNY - 1), cx = xx < 0 ? 0 : xx;
                    pR[k] = p_src[cy * GNX + cx];
                }
            }
        }
#pragma unroll
        for (int k = 0; k < 7; ++k) {
            int i = j + 192 * k;
            if (i < 1156) {
                int wy = i / 34, wx = i - wy * 34;
                int yy = y0 - 1 + wy, xx = x0 - 1 + wx;
                float v = 0.0f;
                if (xx < GNX) {
                    int cy = min(max(yy, 0), GNY - 1), cx = xx < 0 ? 0 : xx;
                    v = b[cy * GNX + cx];
                }
                gB[wy * 35 + wx] = v;
            }
        }
    }
    __syncthreads();

    // w2 (all threads; reads w3v + global r2)
    int w2ylo = 8*by - 1, w2xlo = 8*bx - 1;
    int w3ylo_ = 4*by - 1, w3xlo_ = 4*bx - 1;
    if (t < 100) { int gy = w2ylo + t/10, gx = w2xlo + t%10;
        w2v[t] = (gy >= 0 && gy < 256 && gx >= 0 && gx < 512)
            ? up_val([&](int py, int px) { return w3v[(py - w3ylo_)*6 + (px - w3xlo_)]; },
                     r2[gy*512 + gx], 256, 512, gy, gx) : 0.0f; }
    __syncthreads();
    // w1 (all threads; reads w2v + global r1)
    for (int i = t; i < 324; i += 256) { int gy = w1ylo + i/18, gx = w1xlo + i%18;
        w1v[i] = (gy >= 0 && gy < 512 && gx >= 0 && gx < 1024)
            ? up_val([&](int py, int px) { return w2v[(py - w2ylo)*10 + (px - w2xlo)]; },
                     r1[gy*1024 + gx], 512, 1024, gy, gx) : 0.0f; }
    __syncthreads();

    // phase 3a: sPp = bc_p-mapped p' = p - P(a1) (waves 1-3, p from registers)
    if (t >= 64) {
        int j = t - 64;
#pragma unroll
        for (int k = 0; k < 7; ++k) {
            int i = j + 192 * k;
            if (i < 1296) {
                int wy = i / 36, wx = i - wy * 36;
                int yy = y0 - 2 + wy, xx = x0 - 2 + wx;
                float v = 0.0f;
                if (xx < GNX) {
                    int cy = min(max(yy, 0), GNY - 1), cx = xx < 0 ? 0 : xx;
                    v = pR[k] - w1v[((cy >> 1) - w1ylo)*18 + ((cx >> 1) - w1xlo)];
                }
                sPp[wy*37 + wx] = v;
            }
        }
    }
    __syncthreads();
    // phase 3b: sPn = bc_p-mapped p_next on 34x34 (clamp-then-stencil; b from LDS)
    for (int i = t; i < 1156; i += 256) {
        int wy = i / 34, wx = i - wy * 34;
        int yy = y0 - 1 + wy, xx = x0 - 1 + wx;
        float v = 0.0f;
        if (xx < GNX) {
            int cy = min(max(yy, 0), GNY - 1);
            int cx = xx < 0 ? 0 : xx;
            int rb = cy - y0 + 2, cb = cx - x0 + 2;   // sPp coords of clamped center
            float m[3][3];
#pragma unroll
            for (int dy = 0; dy < 3; ++dy)
#pragma unroll
                for (int dx = 0; dx < 3; ++dx)
                    m[dy][dx] = sPp[(rb + dy - 1)*37 + (cb + dx - 1)];
            float conv = (m[0][0] + m[0][1] + m[0][2] + m[1][0] + m[1][2]
                          + m[2][0] + m[2][1] + m[2][2] - 8.0f*m[1][1]) * (1.0f / 3.0f);
            v = m[1][1] - conv * INV_DIAG + gB[wy*35 + wx] * INV_DIAG;
        }
        sPn[wy*35 + wx] = v;
    }
    __syncthreads();
    // write own p tile
    for (int i = t; i < 1024; i += 256) {
        int ty = i >> 5, tx = i & 31;
        p_dst[(y0 + ty)*GNX + x0 + tx] = sPn[(ty + 1)*35 + (tx + 1)];
    }

    if (!last) {
        // next-iteration residual on tile + restriction (b from LDS)
        for (int i = t; i < 1024; i += 256) {
            int ty = i >> 5, tx = i & 31;
            float m[3][3];
#pragma unroll
            for (int dy = 0; dy < 3; ++dy)
#pragma unroll
                for (int dx = 0; dx < 3; ++dx)
                    m[dy][dx] = sPn[(ty + dy)*35 + (tx + dx)];
            s0[ty*33 + tx] = conv_d3(m) - gB[(ty + 1)*35 + (tx + 1)];
        }
        __syncthreads();
        { int qy = t >> 4, qx = t & 15;
          float v = 0.25f * (s0[(2*qy)*33 + 2*qx] + s0[(2*qy)*33 + 2*qx + 1]
                           + s0[(2*qy+1)*33 + 2*qx] + s0[(2*qy+1)*33 + 2*qx + 1]);
          s1[qy*17 + qx] = v;
          o1[(by*16 + qy)*1024 + bx*16 + qx] = v; }
        __syncthreads();
        if (t < 64) { int qy = t >> 3, qx = t & 7;
          float v = 0.25f * (s1[(2*qy)*17 + 2*qx] + s1[(2*qy)*17 + 2*qx + 1]
                           + s1[(2*qy+1)*17 + 2*qx] + s1[(2*qy+1)*17 + 2*qx + 1]);
          s2[qy*9 + qx] = v;
          o2[(by*8 + qy)*512 + bx*8 + qx] = v; }
        __syncthreads();
        if (t < 16) { int qy = t >> 2, qx = t & 3;
          float v = 0.25f * (s2[(2*qy)*9 + 2*qx] + s2[(2*qy)*9 + 2*qx + 1]
                           + s2[(2*qy+1)*9 + 2*qx] + s2[(2*qy+1)*9 + 2*qx + 1]);
          s3[qy*5 + qx] = v;
          o3[(by*4 + qy)*256 + bx*4 + qx] = v; }
        __syncthreads();
        if (t < 4) { int qy = t >> 1, qx = t & 1;
          float v = 0.25f * (s3[(2*qy)*5 + 2*qx] + s3[(2*qy)*5 + 2*qx + 1]
                           + s3[(2*qy+1)*5 + 2*qx] + s3[(2*qy+1)*5 + 2*qx + 1]);
          s4[qy*3 + qx] = v;
          o4[(by*2 + qy)*128 + bx*2 + qx] = v; }
        __syncthreads();
        if (t == 0)
            o5[by*64 + bx] = 0.25f * (s4[0] + s4[1] + s4[3] + s4[4]);
    } else {
        // fused projection
        for (int i = t; i < 1024; i += 256) {
            int ty = i >> 5, tx = i & 31;
            float m[3][3];
#pragma unroll
            for (int dy = 0; dy < 3; ++dy)
#pragma unroll
                for (int dx = 0; dx < 3; ++dx)
                    m[dy][dx] = sPn[(ty + dy)*35 + (tx + dx)];
            int idx = (y0 + ty)*GNX + x0 + tx;
            float damp = 1.0f / (1.0f + DT * sigma[idx]);
            u_io[idx] = (u_io[idx] - conv_x3(m) * DT) * damp;
            v_io[idx] = (v_io[idx] - conv_y3(m) * DT) * damp;
        }
    }
}

extern "C" void kernel_launch(void* const* d_in, const int* in_sizes, int n_in,
                              void* d_out, int out_size, void* d_ws, size_t ws_size,
                              hipStream_t stream) {
    (void)in_sizes; (void)n_in; (void)out_size; (void)ws_size;
    const float* u_in  = (const float*)d_in[0];
    const float* v_in  = (const float*)d_in[1];
    const float* p_in  = (const float*)d_in[2];
    const float* sigma = (const float*)d_in[3];

    float* out_u = (float*)d_out;
    float* out_v = out_u + GNPTS;
    float* out_p = out_u + 2 * (size_t)GNPTS;

    float* ws   = (float*)d_ws;
    float* b    = ws;
    float* p_ws = b + (size_t)GNPTS;
    float* base = p_ws + (size_t)GNPTS;
    float* A_[5], * B_[5];
    size_t lsz[5] = {524288, 131072, 32768, 8192, 2048};
    float* cur = base;
    for (int l = 0; l < 5; ++l) { A_[l] = cur; cur += lsz[l]; }
    for (int l = 0; l < 5; ++l) { B_[l] = cur; cur += lsz[l]; }

    dim3 grdT(GNX / 32, GNY / 32), blkT(256);

    k_front<<<grdT, blkT, 0, stream>>>(u_in, v_in, p_in, sigma,
                                       out_u, out_v, b,
                                       A_[0], A_[1], A_[2], A_[3], A_[4]);

    const float* p_cur = p_in;
    float* p_bufs[2] = { out_p, p_ws };   // it0->out_p, it1->p_ws, ..., it4->out_p
    for (int it = 0; it < 5; ++it) {
        float** rp = (it % 2 == 0) ? A_ : B_;
        float** wp = (it % 2 == 0) ? B_ : A_;
        float* p_next = p_bufs[it % 2];
        int last = (it == 4) ? 1 : 0;
        k_mg<<<grdT, blkT, 0, stream>>>(p_cur, b,
                                        rp[0], rp[1], rp[2], rp[3], rp[4],
                                        p_next,
                                        wp[0], wp[1], wp[2], wp[3], wp[4],
                                        sigma, out_u, out_v, last);
        p_cur = p_next;
    }
}

// Round 12
// 219.938 us; speedup vs baseline: 1.1406x; 1.0008x over previous
//
#include <hip/hip_runtime.h>
#include <cstdint>

#define GNY 1024
#define GNX 2048
#define GNPTS (GNY * GNX)

namespace {
constexpr float DT = 0.1f;
constexpr float NUc = 0.01f;
constexpr float INV_DIAG = -0.375f;   // 1/DIAG, DIAG = -8/(3*dx^2) = -8/3
}

// ---- boundary-condition index maps (verified against JAX .at[].set order) ----
__device__ __forceinline__ float bc_u_at(const float* __restrict__ f, int y, int x) {
    if (y < 0 || y >= GNY || x < 0) return 1.0f;
    if (x >= GNX) x = GNX - 1;
    return f[y * GNX + x];
}
__device__ __forceinline__ float bc_v_at(const float* __restrict__ f, int y, int x) {
    if (y < 0 || y >= GNY || x < 0) return 0.0f;
    if (x >= GNX) x = GNX - 1;
    return f[y * GNX + x];
}
__device__ __forceinline__ float bc_p_at(const float* __restrict__ f, int y, int x) {
    if (x >= GNX) return 0.0f;          // right ghost = 0 (dominates corners)
    if (x < 0) x = 0;
    y = min(max(y, 0), GNY - 1);
    return f[y * GNX + x];
}

// ---- stencils (cross-correlation, m[dy][dx] = f(y+dy-1, x+dx-1)) ----
__device__ __forceinline__ float conv_x3(const float m[3][3]) {
    return ((m[0][2] - m[0][0]) + 4.0f * (m[1][2] - m[1][0]) + (m[2][2] - m[2][0])) * (1.0f / 12.0f);
}
__device__ __forceinline__ float conv_y3(const float m[3][3]) {
    return ((m[2][0] - m[0][0]) + 4.0f * (m[2][1] - m[0][1]) + (m[2][2] - m[0][2])) * (1.0f / 12.0f);
}
__device__ __forceinline__ float conv_d3(const float m[3][3]) {
    return (m[0][0] + m[0][1] + m[0][2] + m[1][0] + m[1][2] + m[2][0] + m[2][1] + m[2][2]
            - 8.0f * m[1][1]) * (1.0f / 3.0f);
}

// strip helpers: b0/b1/b2 are 3 rows x 6 cols covering outputs k=0..3
__device__ __forceinline__ float strip_d3(const float* b0, const float* b1, const float* b2, int k) {
    float cs0 = b0[k] + b1[k] + b2[k];
    float cs1 = b0[k+1] + b1[k+1] + b2[k+1];
    float cs2 = b0[k+2] + b1[k+2] + b2[k+2];
    return (cs0 + cs1 + cs2 - 9.0f * b1[k+1]) * (1.0f / 3.0f);
}
__device__ __forceinline__ float strip_x3(const float* b0, const float* b1, const float* b2, int k) {
    return ((b0[k+2] + 4.0f*b1[k+2] + b2[k+2]) - (b0[k] + 4.0f*b1[k] + b2[k])) * (1.0f / 12.0f);
}
__device__ __forceinline__ float strip_y3(const float* b0, const float* b1, const float* b2, int k) {
    return ((b2[k] - b0[k]) + 4.0f*(b2[k+1] - b0[k+1]) + (b2[k+2] - b0[k+2])) * (1.0f / 12.0f);
}
#define STRIP_LOAD(arr, base, stride) \
    { _Pragma("unroll") for (int j = 0; j < 6; ++j) { \
        b0[j] = arr[(base) + j]; b1[j] = arr[(base) + (stride) + j]; b2[j] = arr[(base) + 2*(stride) + j]; } }

// ---- FUSED front-end; interior blocks use 4-wide stencil strips ----
__global__ __launch_bounds__(256) void k_front(
        const float* __restrict__ u, const float* __restrict__ v,
        const float* __restrict__ p, const float* __restrict__ sigma,
        float* __restrict__ u2g, float* __restrict__ v2g, float* __restrict__ bg,
        float* __restrict__ r1, float* __restrict__ r2, float* __restrict__ r3,
        float* __restrict__ r4, float* __restrict__ r5) {
    __shared__ float scrF[7110];
    float* sP    = scrF;              // 38x38 stride 39 (1482), origin (y0-3,x0-3)
    float* sU    = scrF + 1482;
    float* sV    = scrF + 2964;
    float* sU2   = scrF + 1482;       // overlay, 34x35 (1190), origin (y0-1,x0-1)
    float* sV2   = scrF + 2672;
    float* sBu   = scrF + 4446;       // 36x37 (1332), origin (y0-2,x0-2)
    float* sBv   = scrF + 5778;
    float* s0    = scrF + 4446;       // overlay: 32x33 (1056)
    float* s1    = scrF + 5502;       // 16x17 (272)
    float* s2    = scrF + 5774;       // 8x9 (72)
    float* s3    = scrF + 5846;       // 4x5 (20)
    float* s4    = scrF + 5866;       // 2x3 (6)

    int t = threadIdx.x;
    int bx = blockIdx.x, by = blockIdx.y;
    int y0 = by * 32, x0 = bx * 32;
    bool edge = !(bx >= 1 && bx <= 62 && by >= 1 && by <= 30);
    bool rightcol = (bx == 63);

    // ---- staging: bc-mapped u/v/p on 38x38 ----
    if (!edge) {
        for (int i = t; i < 1444; i += 256) {
            int wy = i / 38, wx = i - wy * 38;
            int idx = (y0 - 3 + wy) * GNX + (x0 - 3 + wx);
            sP[wy * 39 + wx] = p[idx];
            sU[wy * 39 + wx] = u[idx];
            sV[wy * 39 + wx] = v[idx];
        }
    } else {
        for (int i = t; i < 1444; i += 256) {
            int wy = i / 38, wx = i - wy * 38;
            int gy = y0 - 3 + wy, gx = x0 - 3 + wx;
            sP[wy * 39 + wx] = bc_p_at(p, gy, gx);
            sU[wy * 39 + wx] = bc_u_at(u, gy, gx);
            sV[wy * 39 + wx] = bc_v_at(v, gy, gx);
        }
    }
    __syncthreads();

    // ---- phase A: predictor on 36x36 window ----
    if (!edge) {
        // 324 strips (36 rows x 9 strips of 4)
        for (int s = t; s < 324; s += 256) {
            int ay = s / 9, ax0 = (s - (s / 9) * 9) * 4;
            int base = ay * 39 + ax0;
            float b0[6], b1[6], b2[6];
            float d3u[4], x3u[4], y3u[4], uc4[4];
            STRIP_LOAD(sU, base, 39)
#pragma unroll
            for (int k = 0; k < 4; ++k) {
                uc4[k] = b1[k+1];
                d3u[k] = strip_d3(b0, b1, b2, k);
                x3u[k] = strip_x3(b0, b1, b2, k);
                y3u[k] = strip_y3(b0, b1, b2, k);
            }
            float d3v[4], x3v[4], y3v[4], vc4[4];
            STRIP_LOAD(sV, base, 39)
#pragma unroll
            for (int k = 0; k < 4; ++k) {
                vc4[k] = b1[k+1];
                d3v[k] = strip_d3(b0, b1, b2, k);
                x3v[k] = strip_x3(b0, b1, b2, k);
                y3v[k] = strip_y3(b0, b1, b2, k);
            }
            float gx4[4], gy4[4];
            STRIP_LOAD(sP, base, 39)
#pragma unroll
            for (int k = 0; k < 4; ++k) {
                gx4[k] = strip_x3(b0, b1, b2, k) * DT;
                gy4[k] = strip_y3(b0, b1, b2, k) * DT;
            }
#pragma unroll
            for (int k = 0; k < 4; ++k) {
                int gy = y0 - 2 + ay, gx = x0 - 2 + ax0 + k;
                float dampv = 1.0f / (1.0f + DT * sigma[gy * GNX + gx]);
                float buv = (uc4[k] + 0.5f * (NUc * d3u[k] * DT - uc4[k] * x3u[k] * DT - vc4[k] * y3u[k] * DT) - gx4[k]) * dampv;
                float bvv = (vc4[k] + 0.5f * (NUc * d3v[k] * DT - uc4[k] * x3v[k] * DT - vc4[k] * y3v[k] * DT) - gy4[k]) * dampv;
                sBu[ay * 37 + ax0 + k] = buv;
                sBv[ay * 37 + ax0 + k] = bvv;
            }
        }
    } else {
        for (int i = t; i < 1296; i += 256) {
            int ay = i / 36, ax = i - ay * 36;
            int gy = y0 - 2 + ay, gx = x0 - 2 + ax;
            float un[3][3], vn[3][3], pn[3][3];
#pragma unroll
            for (int dy = 0; dy < 3; ++dy)
#pragma unroll
                for (int dx = 0; dx < 3; ++dx) {
                    int li = (ay + dy) * 39 + ax + dx;
                    un[dy][dx] = sU[li]; vn[dy][dx] = sV[li]; pn[dy][dx] = sP[li];
                }
            float buv, bvv;
            bool valid = (gy >= 0 && gy < GNY && gx >= 0 && gx < GNX);
            if (valid) {
                float dampv = 1.0f / (1.0f + DT * sigma[gy * GNX + gx]);
                float gxp = conv_x3(pn) * DT, gyp = conv_y3(pn) * DT;
                float uc = un[1][1], vc = vn[1][1];
                buv = (uc + 0.5f * (NUc * conv_d3(un) * DT - uc * conv_x3(un) * DT - vc * conv_y3(un) * DT) - gxp) * dampv;
                bvv = (vc + 0.5f * (NUc * conv_d3(vn) * DT - uc * conv_x3(vn) * DT - vc * conv_y3(vn) * DT) - gyp) * dampv;
            } else if (gy < 0 || gy >= GNY || gx < 0) {
                buv = 1.0f; bvv = 0.0f;
            } else {
                buv = 0.0f; bvv = 0.0f;
            }
            sBu[ay * 37 + ax] = buv;
            sBv[ay * 37 + ax] = bvv;
        }
    }
    __syncthreads();

    // ---- phase B: corrector on 34x34 window ----
    float ucS[2][4], vcS[2][4];   // strip preload (interior)
    float ucA[5], vcA[5];          // per-point preload (edge)
    if (!edge) {
        int ns = 0;
        for (int s = t; s < 306; s += 256, ++ns) {
            int cy = s / 9, cx0 = (s - (s / 9) * 9) * 4;
#pragma unroll
            for (int k = 0; k < 4; ++k) {
                if (cx0 + k < 34) {
                    int li = (cy + 2) * 39 + cx0 + 2 + k;
                    ucS[ns][k] = sU[li]; vcS[ns][k] = sV[li];
                }
            }
        }
    } else {
        int np = 0;
        for (int i = t; i < 1156; i += 256, ++np) {
            int cy = i / 34, cx = i - cy * 34;
            int li = (cy + 2) * 39 + cx + 2;
            ucA[np] = sU[li]; vcA[np] = sV[li];
        }
    }
    __syncthreads();
    if (!edge) {
        int ns = 0;
        for (int s = t; s < 306; s += 256, ++ns) {
            int cy = s / 9, cx0 = (s - (s / 9) * 9) * 4;
            int baseB = cy * 37 + cx0;
            int baseP = (cy + 1) * 39 + cx0 + 1;
            float b0[6], b1[6], b2[6];
            float d3bu[4], x3bu[4], y3bu[4], buc4[4];
            STRIP_LOAD(sBu, baseB, 37)
#pragma unroll
            for (int k = 0; k < 4; ++k) {
                buc4[k] = b1[k+1];
                d3bu[k] = strip_d3(b0, b1, b2, k);
                x3bu[k] = strip_x3(b0, b1, b2, k);
                y3bu[k] = strip_y3(b0, b1, b2, k);
            }
            float d3bv[4], x3bv[4], y3bv[4], bvc4[4];
            STRIP_LOAD(sBv, baseB, 37)
#pragma unroll
            for (int k = 0; k < 4; ++k) {
                bvc4[k] = b1[k+1];
                d3bv[k] = strip_d3(b0, b1, b2, k);
                x3bv[k] = strip_x3(b0, b1, b2, k);
                y3bv[k] = strip_y3(b0, b1, b2, k);
            }
            float gx4[4], gy4[4];
            STRIP_LOAD(sP, baseP, 39)
#pragma unroll
            for (int k = 0; k < 4; ++k) {
                gx4[k] = strip_x3(b0, b1, b2, k) * DT;
                gy4[k] = strip_y3(b0, b1, b2, k) * DT;
            }
#pragma unroll
            for (int k = 0; k < 4; ++k) {
                if (cx0 + k < 34) {
                    int cy_ = cy, cx_ = cx0 + k;
                    int gyy = y0 - 1 + cy_, gxx = x0 - 1 + cx_;
                    int idx = gyy * GNX + gxx;
                    float dampv = 1.0f / (1.0f + DT * sigma[idx]);
                    float u2_ = (ucS[ns][k] + NUc * d3bu[k] * DT - buc4[k] * x3bu[k] * DT - bvc4[k] * y3bu[k] * DT - gx4[k]) * dampv;
                    float v2_ = (vcS[ns][k] + NUc * d3bv[k] * DT - buc4[k] * x3bv[k] * DT - bvc4[k] * y3bv[k] * DT - gy4[k]) * dampv;
                    if (cy_ >= 1 && cy_ <= 32 && cx_ >= 1 && cx_ <= 32) {
                        u2g[idx] = u2_; v2g[idx] = v2_;
                    }
                    sU2[cy_ * 35 + cx_] = u2_;
                    sV2[cy_ * 35 + cx_] = v2_;
                }
            }
        }
    } else {
        int np = 0;
        for (int i = t; i < 1156; i += 256, ++np) {
            int cy = i / 34, cx = i - cy * 34;
            int gy = y0 - 1 + cy, gx = x0 - 1 + cx;
            float u2_ = 0.0f, v2_ = 0.0f;
            bool valid = (gy >= 0 && gy < GNY && gx >= 0 && gx < GNX);
            if (valid) {
                float bun[3][3], bvn[3][3], pn[3][3];
                if (!rightcol) {
#pragma unroll
                    for (int dy = 0; dy < 3; ++dy)
#pragma unroll
                        for (int dx = 0; dx < 3; ++dx) {
                            int li = (cy + dy) * 37 + cx + dx;
                            bun[dy][dx] = sBu[li]; bvn[dy][dx] = sBv[li];
                            pn[dy][dx] = sP[(cy + dy + 1) * 39 + cx + dx + 1];
                        }
                } else {
#pragma unroll
                    for (int dy = 0; dy < 3; ++dy)
#pragma unroll
                        for (int dx = 0; dx < 3; ++dx) {
                            int yy = gy + dy - 1, xx = gx + dx - 1;
                            pn[dy][dx] = sP[(cy + dy + 1) * 39 + cx + dx + 1];
                            if (yy < 0 || yy >= GNY || xx < 0) { bun[dy][dx] = 1.0f; bvn[dy][dx] = 0.0f; }
                            else {
                                int cxx = (xx >= GNX) ? GNX - 1 : xx;
                                int li = (cy + dy) * 37 + (cxx - (x0 - 2));
                                bun[dy][dx] = sBu[li]; bvn[dy][dx] = sBv[li];
                            }
                        }
                }
                int idx = gy * GNX + gx;
                float gxp = conv_x3(pn) * DT, gyp = conv_y3(pn) * DT;
                float dampv = 1.0f / (1.0f + DT * sigma[idx]);
                float buc = bun[1][1], bvc = bvn[1][1];
                u2_ = (ucA[np] + NUc * conv_d3(bun) * DT - buc * conv_x3(bun) * DT - bvc * conv_y3(bun) * DT - gxp) * dampv;
                v2_ = (vcA[np] + NUc * conv_d3(bvn) * DT - buc * conv_x3(bvn) * DT - bvc * conv_y3(bvn) * DT - gyp) * dampv;
                if (cy >= 1 && cy <= 32 && cx >= 1 && cx <= 32) {
                    u2g[idx] = u2_; v2g[idx] = v2_;
                }
            } else if (gy < 0 || gy >= GNY || gx < 0) {
                u2_ = 1.0f; v2_ = 0.0f;
            }
            sU2[cy * 35 + cx] = u2_;
            sV2[cy * 35 + cx] = v2_;
        }
    }
    __syncthreads();

    // ---- phase C: b on tile + r0 = A p - b ----
    if (!rightcol) {
        // 256 strips (32 rows x 8), one per thread — valid for ALL non-rightcol
        // blocks since sU2/sV2 already hold bc ghosts and sP is bc-mapped.
        int ty = t >> 3, tx0 = (t & 7) * 4;
        int baseU = ty * 35 + tx0;
        int baseP = (ty + 2) * 39 + tx0 + 2;
        float b0[6], b1[6], b2[6];
        float x3u[4];
        STRIP_LOAD(sU2, baseU, 35)
#pragma unroll
        for (int k = 0; k < 4; ++k) x3u[k] = strip_x3(b0, b1, b2, k);
        float y3v[4];
        STRIP_LOAD(sV2, baseU, 35)
#pragma unroll
        for (int k = 0; k < 4; ++k) y3v[k] = strip_y3(b0, b1, b2, k);
        float d3p[4];
        STRIP_LOAD(sP, baseP, 39)
#pragma unroll
        for (int k = 0; k < 4; ++k) d3p[k] = strip_d3(b0, b1, b2, k);
#pragma unroll
        for (int k = 0; k < 4; ++k) {
            float b_ = -(x3u[k] + y3v[k]) * (1.0f / DT);
            bg[(y0 + ty) * GNX + x0 + tx0 + k] = b_;
            s0[ty * 33 + tx0 + k] = d3p[k] - b_;
        }
    } else {
        for (int i = t; i < 1024; i += 256) {
            int ty = i >> 5, tx = i & 31;
            int gy = y0 + ty, gx = x0 + tx;
            float un[3][3], vn[3][3], pn[3][3];
#pragma unroll
            for (int dy = 0; dy < 3; ++dy)
#pragma unroll
                for (int dx = 0; dx < 3; ++dx) {
                    int yy = gy + dy - 1, xx = gx + dx - 1;
                    pn[dy][dx] = sP[(ty + dy + 2) * 39 + tx + dx + 2];
                    if (yy < 0 || yy >= GNY || xx < 0) { un[dy][dx] = 1.0f; vn[dy][dx] = 0.0f; }
                    else {
                        int cxx = (xx >= GNX) ? GNX - 1 : xx;
                        int li = (ty + dy) * 35 + (cxx - (x0 - 1));
                        un[dy][dx] = sU2[li]; vn[dy][dx] = sV2[li];
                    }
                }
            float b_ = -(conv_x3(un) + conv_y3(vn)) * (1.0f / DT);
            bg[gy * GNX + gx] = b_;
            s0[ty * 33 + tx] = conv_d3(pn) - b_;
        }
    }
    __syncthreads();

    // ---- restriction chain r0 -> r1..r5 ----
    { int qy = t >> 4, qx = t & 15;
      float vv = 0.25f * (s0[(2*qy)*33 + 2*qx] + s0[(2*qy)*33 + 2*qx + 1]
                        + s0[(2*qy+1)*33 + 2*qx] + s0[(2*qy+1)*33 + 2*qx + 1]);
      s1[qy*17 + qx] = vv;
      r1[(by*16 + qy)*1024 + bx*16 + qx] = vv; }
    __syncthreads();
    if (t < 64) { int qy = t >> 3, qx = t & 7;
      float vv = 0.25f * (s1[(2*qy)*17 + 2*qx] + s1[(2*qy)*17 + 2*qx + 1]
                        + s1[(2*qy+1)*17 + 2*qx] + s1[(2*qy+1)*17 + 2*qx + 1]);
      s2[qy*9 + qx] = vv;
      r2[(by*8 + qy)*512 + bx*8 + qx] = vv; }
    __syncthreads();
    if (t < 16) { int qy = t >> 2, qx = t & 3;
      float vv = 0.25f * (s2[(2*qy)*9 + 2*qx] + s2[(2*qy)*9 + 2*qx + 1]
                        + s2[(2*qy+1)*9 + 2*qx] + s2[(2*qy+1)*9 + 2*qx + 1]);
      s3[qy*5 + qx] = vv;
      r3[(by*4 + qy)*256 + bx*4 + qx] = vv; }
    __syncthreads();
    if (t < 4) { int qy = t >> 1, qx = t & 1;
      float vv = 0.25f * (s3[(2*qy)*5 + 2*qx] + s3[(2*qy)*5 + 2*qx + 1]
                        + s3[(2*qy+1)*5 + 2*qx] + s3[(2*qy+1)*5 + 2*qx + 1]);
      s4[qy*3 + qx] = vv;
      r4[(by*2 + qy)*128 + bx*2 + qx] = vv; }
    __syncthreads();
    if (t == 0)
        r5[by*64 + bx] = 0.25f * (s4[0] + s4[1] + s4[3] + s4[4]);
}

// ---- ONE fused MG iteration; strips in 3b/resid/projection ----
__global__ __launch_bounds__(256) void k_mg(
        const float* __restrict__ p_src, const float* __restrict__ b,
        const float* __restrict__ r1, const float* __restrict__ r2,
        const float* __restrict__ r3, const float* __restrict__ r4,
        const float* __restrict__ r5,
        float* __restrict__ p_dst,
        float* __restrict__ o1, float* __restrict__ o2, float* __restrict__ o3,
        float* __restrict__ o4, float* __restrict__ o5,
        const float* __restrict__ sigma, float* __restrict__ u_io,
        float* __restrict__ v_io, int last) {
    __shared__ float scr[3948];
    __shared__ float w6v[9], w5v[9], w4v[16], w3v[36], w2v[100], w1v[324];
    float* s5  = scr;            // 32x64 = 2048
    float* s6  = scr + 2048;     // 512
    float* s7  = scr + 2560;     // 128
    float* s8  = scr + 2688;     // 32
    float* s9  = scr + 2720;     // 8
    float* s10 = scr + 2728;     // 2
    float* a9  = scr + 2730;     // 8
    float* a8  = scr + 2738;     // 32
    float* a7  = scr + 2770;     // 128
    float* sPp = scr;            // 36x36, stride 37 = 1332
    float* sPn = scr + 1332;     // 34x34, stride 35 = 1190
    float* s0  = scr + 2522;     // 1056
    float* s1  = scr + 3578;     // 272
    float* s2  = scr + 3850;     // 72
    float* s3  = scr + 3922;     // 20
    float* s4  = scr + 3942;     // 6

    int t = threadIdx.x;
    int bx = blockIdx.x, by = blockIdx.y;
    int y0 = by * 32, x0 = bx * 32;
    bool interior = (bx >= 1 && bx <= 62 && by >= 1 && by <= 30);

    // phase 1: full restriction r5 -> r10, tiny full up levels a10->a7
    for (int i = t; i < 2048; i += 256) s5[i] = r5[i];
    __syncthreads();
    for (int i = t; i < 512; i += 256) {
        int y = i >> 5, x = i & 31;
        s6[i] = 0.25f * (s5[(2*y)*64 + 2*x] + s5[(2*y)*64 + 2*x + 1]
                       + s5[(2*y+1)*64 + 2*x] + s5[(2*y+1)*64 + 2*x + 1]);
    }
    __syncthreads();
    if (t < 128) { int y = t >> 4, x = t & 15;
        s7[t] = 0.25f * (s6[(2*y)*32 + 2*x] + s6[(2*y)*32 + 2*x + 1]
                       + s6[(2*y+1)*32 + 2*x] + s6[(2*y+1)*32 + 2*x + 1]); }
    __syncthreads();
    if (t < 32) { int y = t >> 3, x = t & 7;
        s8[t] = 0.25f * (s7[(2*y)*16 + 2*x] + s7[(2*y)*16 + 2*x + 1]
                       + s7[(2*y+1)*16 + 2*x] + s7[(2*y+1)*16 + 2*x + 1]); }
    __syncthreads();
    if (t < 8) { int y = t >> 2, x = t & 3;
        s9[t] = 0.25f * (s8[(2*y)*8 + 2*x] + s8[(2*y)*8 + 2*x + 1]
                       + s8[(2*y+1)*8 + 2*x] + s8[(2*y+1)*8 + 2*x + 1]); }
    __syncthreads();
    if (t < 2)
        s10[t] = 0.25f * (s9[2*t] + s9[2*t + 1] + s9[4 + 2*t] + s9[4 + 2*t + 1]);
    __syncthreads();

    // up_val inline: a = P(par) - conv(bc0(P(par)))/DIAG + r/DIAG
    auto upv = [&](auto pget, float rval, int H, int W, int y, int x) -> float {
        float m[3][3];
#pragma unroll
        for (int dy = 0; dy < 3; ++dy)
#pragma unroll
            for (int dx = 0; dx < 3; ++dx) {
                int yy = y + dy - 1, xx = x + dx - 1;
                m[dy][dx] = (yy >= 0 && yy < H && xx >= 0 && xx < W) ? pget(yy >> 1, xx >> 1) : 0.0f;
            }
        float conv = (m[0][0] + m[0][1] + m[0][2] + m[1][0] + m[1][2]
                      + m[2][0] + m[2][1] + m[2][2] - 8.0f * m[1][1]) * (1.0f / 3.0f);
        return m[1][1] - conv * INV_DIAG + rval * INV_DIAG;
    };

    if (t < 8) { int y = t >> 2, x = t & 3;
        a9[t] = upv([&](int py, int px) { return s10[py*2 + px] * INV_DIAG; },
                    s9[t], 2, 4, y, x); }
    __syncthreads();
    if (t < 32) { int y = t >> 3, x = t & 7;
        a8[t] = upv([&](int py, int px) { return a9[py*4 + px]; },
                    s8[t], 4, 8, y, x); }
    __syncthreads();
    if (t < 128) { int y = t >> 4, x = t & 15;
        a7[t] = upv([&](int py, int px) { return a8[py*8 + px]; },
                    s7[t], 8, 16, y, x); }
    __syncthreads();

    // phase 2: windowed up-sweep a6..a1
    int w6ylo = (by - 2) >> 1, w6xlo = (bx - 2) >> 1;
    int w5ylo = by - 1,        w5xlo = bx - 1;
    int w4ylo = 2*by - 1,      w4xlo = 2*bx - 1;
    int w3ylo = 4*by - 1,      w3xlo = 4*bx - 1;
    int w2ylo = 8*by - 1,      w2xlo = 8*bx - 1;
    int w1ylo = 16*by - 1,     w1xlo = 16*bx - 1;

    if (t < 9) { int gy = w6ylo + t/3, gx = w6xlo + t%3;
        w6v[t] = (gy >= 0 && gy < 16 && gx >= 0 && gx < 32)
            ? upv([&](int py, int px) { return a7[py*16 + px]; },
                  s6[gy*32 + gx], 16, 32, gy, gx) : 0.0f; }
    __syncthreads();
    if (t < 9) { int gy = w5ylo + t/3, gx = w5xlo + t%3;
        w5v[t] = (gy >= 0 && gy < 32 && gx >= 0 && gx < 64)
            ? upv([&](int py, int px) { return w6v[(py - w6ylo)*3 + (px - w6xlo)]; },
                  s5[gy*64 + gx], 32, 64, gy, gx) : 0.0f; }
    __syncthreads();
    if (t < 16) { int gy = w4ylo + t/4, gx = w4xlo + t%4;
        w4v[t] = (gy >= 0 && gy < 64 && gx >= 0 && gx < 128)
            ? upv([&](int py, int px) { return w5v[(py - w5ylo)*3 + (px - w5xlo)]; },
                  r4[gy*128 + gx], 64, 128, gy, gx) : 0.0f; }
    __syncthreads();
    if (t < 36) { int gy = w3ylo + t/6, gx = w3xlo + t%6;
        w3v[t] = (gy >= 0 && gy < 128 && gx >= 0 && gx < 256)
            ? upv([&](int py, int px) { return w4v[(py - w4ylo)*4 + (px - w4xlo)]; },
                  r3[gy*256 + gx], 128, 256, gy, gx) : 0.0f; }
    __syncthreads();
    if (t < 100) { int gy = w2ylo + t/10, gx = w2xlo + t%10;
        w2v[t] = (gy >= 0 && gy < 256 && gx >= 0 && gx < 512)
            ? upv([&](int py, int px) { return w3v[(py - w3ylo)*6 + (px - w3xlo)]; },
                  r2[gy*512 + gx], 256, 512, gy, gx) : 0.0f; }
    __syncthreads();
    for (int i = t; i < 324; i += 256) { int gy = w1ylo + i/18, gx = w1xlo + i%18;
        w1v[i] = (gy >= 0 && gy < 512 && gx >= 0 && gx < 1024)
            ? upv([&](int py, int px) { return w2v[(py - w2ylo)*10 + (px - w2xlo)]; },
                  r1[gy*1024 + gx], 512, 1024, gy, gx) : 0.0f; }
    __syncthreads();

    // phase 3a: sPp = bc_p-mapped p' on 36x36 window
    for (int i = t; i < 1296; i += 256) {
        int wy = i / 36, wx = i - wy * 36;
        int yy = y0 - 2 + wy, xx = x0 - 2 + wx;
        float v = 0.0f;
        if (xx < GNX) {
            int cy = min(max(yy, 0), GNY - 1);
            int cx = xx < 0 ? 0 : xx;
            v = p_src[cy*GNX + cx] - w1v[((cy >> 1) - w1ylo)*18 + ((cx >> 1) - w1xlo)];
        }
        sPp[wy*37 + wx] = v;
    }
    __syncthreads();
    // phase 3b: sPn = p_next on 34x34
    if (interior) {
        // no clamps apply: plain taps, strips of 4
        for (int s = t; s < 306; s += 256) {
            int wy = s / 9, wx0 = (s - (s / 9) * 9) * 4;
            int base = wy * 37 + wx0;
            float b0[6], b1[6], b2[6];
            STRIP_LOAD(sPp, base, 37)
#pragma unroll
            for (int k = 0; k < 4; ++k) {
                if (wx0 + k < 34) {
                    float c = b1[k+1];
                    float conv = strip_d3(b0, b1, b2, k);
                    float bvv = b[(y0 - 1 + wy) * GNX + (x0 - 1 + wx0 + k)];
                    sPn[wy * 35 + wx0 + k] = c - conv * INV_DIAG + bvv * INV_DIAG;
                }
            }
        }
    } else {
        for (int i = t; i < 1156; i += 256) {
            int wy = i / 34, wx = i - wy * 34;
            int yy = y0 - 1 + wy, xx = x0 - 1 + wx;
            float v = 0.0f;
            if (xx < GNX) {
                int cy = min(max(yy, 0), GNY - 1);
                int cx = xx < 0 ? 0 : xx;
                int rb = cy - y0 + 2, cb = cx - x0 + 2;
                float m[3][3];
#pragma unroll
                for (int dy = 0; dy < 3; ++dy)
#pragma unroll
                    for (int dx = 0; dx < 3; ++dx)
                        m[dy][dx] = sPp[(rb + dy - 1)*37 + (cb + dx - 1)];
                float conv = (m[0][0] + m[0][1] + m[0][2] + m[1][0] + m[1][2]
                              + m[2][0] + m[2][1] + m[2][2] - 8.0f*m[1][1]) * (1.0f / 3.0f);
                v = m[1][1] - conv * INV_DIAG + b[cy*GNX + cx] * INV_DIAG;
            }
            sPn[wy*35 + wx] = v;
        }
    }
    __syncthreads();
    // write own p tile
    for (int i = t; i < 1024; i += 256) {
        int ty = i >> 5, tx = i & 31;
        p_dst[(y0 + ty)*GNX + x0 + tx] = sPn[(ty + 1)*35 + (tx + 1)];
    }

    if (!last) {
        // next-iteration residual (strips, all blocks) + restriction
        {
            int ty = t >> 3, tx0 = (t & 7) * 4;
            int base = ty * 35 + tx0;
            float b0[6], b1[6], b2[6];
            STRIP_LOAD(sPn, base, 35)
#pragma unroll
            for (int k = 0; k < 4; ++k) {
                float d3 = strip_d3(b0, b1, b2, k);
                s0[ty * 33 + tx0 + k] = d3 - b[(y0 + ty) * GNX + x0 + tx0 + k];
            }
        }
        __syncthreads();
        { int qy = t >> 4, qx = t & 15;
          float v = 0.25f * (s0[(2*qy)*33 + 2*qx] + s0[(2*qy)*33 + 2*qx + 1]
                           + s0[(2*qy+1)*33 + 2*qx] + s0[(2*qy+1)*33 + 2*qx + 1]);
          s1[qy*17 + qx] = v;
          o1[(by*16 + qy)*1024 + bx*16 + qx] = v; }
        __syncthreads();
        if (t < 64) { int qy = t >> 3, qx = t & 7;
          float v = 0.25f * (s1[(2*qy)*17 + 2*qx] + s1[(2*qy)*17 + 2*qx + 1]
                           + s1[(2*qy+1)*17 + 2*qx] + s1[(2*qy+1)*17 + 2*qx + 1]);
          s2[qy*9 + qx] = v;
          o2[(by*8 + qy)*512 + bx*8 + qx] = v; }
        __syncthreads();
        if (t < 16) { int qy = t >> 2, qx = t & 3;
          float v = 0.25f * (s2[(2*qy)*9 + 2*qx] + s2[(2*qy)*9 + 2*qx + 1]
                           + s2[(2*qy+1)*9 + 2*qx] + s2[(2*qy+1)*9 + 2*qx + 1]);
          s3[qy*5 + qx] = v;
          o3[(by*4 + qy)*256 + bx*4 + qx] = v; }
        __syncthreads();
        if (t < 4) { int qy = t >> 1, qx = t & 1;
          float v = 0.25f * (s3[(2*qy)*5 + 2*qx] + s3[(2*qy)*5 + 2*qx + 1]
                           + s3[(2*qy+1)*5 + 2*qx] + s3[(2*qy+1)*5 + 2*qx + 1]);
          s4[qy*3 + qx] = v;
          o4[(by*2 + qy)*128 + bx*2 + qx] = v; }
        __syncthreads();
        if (t == 0)
            o5[by*64 + bx] = 0.25f * (s4[0] + s4[1] + s4[3] + s4[4]);
    } else {
        // fused projection (strips, all blocks)
        int ty = t >> 3, tx0 = (t & 7) * 4;
        int base = ty * 35 + tx0;
        float b0[6], b1[6], b2[6];
        float x3p[4], y3p[4];
        STRIP_LOAD(sPn, base, 35)
#pragma unroll
        for (int k = 0; k < 4; ++k) {
            x3p[k] = strip_x3(b0, b1, b2, k);
            y3p[k] = strip_y3(b0, b1, b2, k);
        }
#pragma unroll
        for (int k = 0; k < 4; ++k) {
            int idx = (y0 + ty) * GNX + x0 + tx0 + k;
            float damp = 1.0f / (1.0f + DT * sigma[idx]);
            u_io[idx] = (u_io[idx] - x3p[k] * DT) * damp;
            v_io[idx] = (v_io[idx] - y3p[k] * DT) * damp;
        }
    }
}

extern "C" void kernel_launch(void* const* d_in, const int* in_sizes, int n_in,
                              void* d_out, int out_size, void* d_ws, size_t ws_size,
                              hipStream_t stream) {
    (void)in_sizes; (void)n_in; (void)out_size; (void)ws_size;
    const float* u_in  = (const float*)d_in[0];
    const float* v_in  = (const float*)d_in[1];
    const float* p_in  = (const float*)d_in[2];
    const float* sigma = (const float*)d_in[3];

    float* out_u = (float*)d_out;
    float* out_v = out_u + GNPTS;
    float* out_p = out_u + 2 * (size_t)GNPTS;

    float* ws   = (float*)d_ws;
    float* b    = ws;
    float* p_ws = b + (size_t)GNPTS;
    float* base = p_ws + (size_t)GNPTS;
    float* A_[5], * B_[5];
    size_t lsz[5] = {524288, 131072, 32768, 8192, 2048};
    float* cur = base;
    for (int l = 0; l < 5; ++l) { A_[l] = cur; cur += lsz[l]; }
    for (int l = 0; l < 5; ++l) { B_[l] = cur; cur += lsz[l]; }

    dim3 grdT(GNX / 32, GNY / 32), blkT(256);

    k_front<<<grdT, blkT, 0, stream>>>(u_in, v_in, p_in, sigma,
                                       out_u, out_v, b,
                                       A_[0], A_[1], A_[2], A_[3], A_[4]);

    const float* p_cur = p_in;
    float* p_bufs[2] = { out_p, p_ws };   // it0->out_p, it1->p_ws, ..., it4->out_p
    for (int it = 0; it < 5; ++it) {
        float** rp = (it % 2 == 0) ? A_ : B_;
        float** wp = (it % 2 == 0) ? B_ : A_;
        float* p_next = p_bufs[it % 2];
        int last = (it == 4) ? 1 : 0;
        k_mg<<<grdT, blkT, 0, stream>>>(p_cur, b,
                                        rp[0], rp[1], rp[2], rp[3], rp[4],
                                        p_next,
                                        wp[0], wp[1], wp[2], wp[3], wp[4],
                                        sigma, out_u, out_v, last);
        p_cur = p_next;
    }
}

// Round 13
// 195.035 us; speedup vs baseline: 1.2863x; 1.1277x over previous
//
#include <hip/hip_runtime.h>
#include <cstdint>

#define GNY 1024
#define GNX 2048
#define GNPTS (GNY * GNX)

namespace {
constexpr float DT = 0.1f;
constexpr float NUc = 0.01f;
constexpr float INV_DIAG = -0.375f;   // 1/DIAG, DIAG = -8/(3*dx^2) = -8/3
}

// XCD-aware swizzle: hardware dispatches block n to XCD n%8 (heuristic);
// give XCD k the contiguous 4-row band by = k*4 + (n/8)/64, bx = (n/8)%64
// so halo/pyramid reads mostly stay in one XCD's L2. Pure permutation.
__device__ __forceinline__ void swizzle_bid(int& bx, int& by) {
    int n = blockIdx.y * 64 + blockIdx.x;
    int i = n >> 3;
    bx = i & 63;
    by = ((n & 7) << 2) | (i >> 6);
}

// ---- boundary-condition index maps (verified against JAX .at[].set order) ----
__device__ __forceinline__ float bc_u_at(const float* __restrict__ f, int y, int x) {
    if (y < 0 || y >= GNY || x < 0) return 1.0f;
    if (x >= GNX) x = GNX - 1;
    return f[y * GNX + x];
}
__device__ __forceinline__ float bc_v_at(const float* __restrict__ f, int y, int x) {
    if (y < 0 || y >= GNY || x < 0) return 0.0f;
    if (x >= GNX) x = GNX - 1;
    return f[y * GNX + x];
}
__device__ __forceinline__ float bc_p_at(const float* __restrict__ f, int y, int x) {
    if (x >= GNX) return 0.0f;          // right ghost = 0 (dominates corners)
    if (x < 0) x = 0;
    y = min(max(y, 0), GNY - 1);
    return f[y * GNX + x];
}

// ---- stencils (cross-correlation, m[dy][dx] = f(y+dy-1, x+dx-1)) ----
__device__ __forceinline__ float conv_x3(const float m[3][3]) {
    return ((m[0][2] - m[0][0]) + 4.0f * (m[1][2] - m[1][0]) + (m[2][2] - m[2][0])) * (1.0f / 12.0f);
}
__device__ __forceinline__ float conv_y3(const float m[3][3]) {
    return ((m[2][0] - m[0][0]) + 4.0f * (m[2][1] - m[0][1]) + (m[2][2] - m[0][2])) * (1.0f / 12.0f);
}
__device__ __forceinline__ float conv_d3(const float m[3][3]) {
    return (m[0][0] + m[0][1] + m[0][2] + m[1][0] + m[1][2] + m[2][0] + m[2][1] + m[2][2]
            - 8.0f * m[1][1]) * (1.0f / 3.0f);
}

// strip helpers: b0/b1/b2 are 3 rows x (W+2) cols; k indexes the output
__device__ __forceinline__ float strip_d3(const float* b0, const float* b1, const float* b2, int k) {
    float cs0 = b0[k] + b1[k] + b2[k];
    float cs1 = b0[k+1] + b1[k+1] + b2[k+1];
    float cs2 = b0[k+2] + b1[k+2] + b2[k+2];
    return (cs0 + cs1 + cs2 - 9.0f * b1[k+1]) * (1.0f / 3.0f);
}
__device__ __forceinline__ float strip_x3(const float* b0, const float* b1, const float* b2, int k) {
    return ((b0[k+2] + 4.0f*b1[k+2] + b2[k+2]) - (b0[k] + 4.0f*b1[k] + b2[k])) * (1.0f / 12.0f);
}
__device__ __forceinline__ float strip_y3(const float* b0, const float* b1, const float* b2, int k) {
    return ((b2[k] - b0[k]) + 4.0f*(b2[k+1] - b0[k+1]) + (b2[k+2] - b0[k+2])) * (1.0f / 12.0f);
}
#define STRIP_LOAD(arr, base, stride) \
    { _Pragma("unroll") for (int j = 0; j < 6; ++j) { \
        b0[j] = arr[(base) + j]; b1[j] = arr[(base) + (stride) + j]; b2[j] = arr[(base) + 2*(stride) + j]; } }
#define STRIP6_LOAD(arr, base, stride) \
    { _Pragma("unroll") for (int j = 0; j < 8; ++j) { \
        b0[j] = arr[(base) + j]; b1[j] = arr[(base) + (stride) + j]; b2[j] = arr[(base) + 2*(stride) + j]; } }

// ---- FUSED front-end; interior blocks use balanced single-pass 6-wide strips ----
__global__ __launch_bounds__(256) void k_front(
        const float* __restrict__ u, const float* __restrict__ v,
        const float* __restrict__ p, const float* __restrict__ sigma,
        float* __restrict__ u2g, float* __restrict__ v2g, float* __restrict__ bg,
        float* __restrict__ r1, float* __restrict__ r2, float* __restrict__ r3,
        float* __restrict__ r4, float* __restrict__ r5) {
    __shared__ float scrF[7120];      // +10 pad: masked 8-wide strip loads stay in-bounds
    float* sP    = scrF;              // 38x38 stride 39 (1482), origin (y0-3,x0-3)
    float* sU    = scrF + 1482;
    float* sV    = scrF + 2964;
    float* sU2   = scrF + 1482;       // overlay, 34x35 (1190), origin (y0-1,x0-1)
    float* sV2   = scrF + 2672;
    float* sBu   = scrF + 4446;       // 36x37 (1332), origin (y0-2,x0-2)
    float* sBv   = scrF + 5778;
    float* s0    = scrF + 4446;       // overlay: 32x33 (1056)
    float* s1    = scrF + 5502;       // 16x17 (272)
    float* s2    = scrF + 5774;       // 8x9 (72)
    float* s3    = scrF + 5846;       // 4x5 (20)
    float* s4    = scrF + 5866;       // 2x3 (6)

    int t = threadIdx.x;
    int bx, by;
    swizzle_bid(bx, by);
    int y0 = by * 32, x0 = bx * 32;
    bool edge = !(bx >= 1 && bx <= 62 && by >= 1 && by <= 30);
    bool rightcol = (bx == 63);

    // ---- staging: bc-mapped u/v/p on 38x38 ----
    if (!edge) {
        for (int i = t; i < 1444; i += 256) {
            int wy = i / 38, wx = i - wy * 38;
            int idx = (y0 - 3 + wy) * GNX + (x0 - 3 + wx);
            sP[wy * 39 + wx] = p[idx];
            sU[wy * 39 + wx] = u[idx];
            sV[wy * 39 + wx] = v[idx];
        }
    } else {
        for (int i = t; i < 1444; i += 256) {
            int wy = i / 38, wx = i - wy * 38;
            int gy = y0 - 3 + wy, gx = x0 - 3 + wx;
            sP[wy * 39 + wx] = bc_p_at(p, gy, gx);
            sU[wy * 39 + wx] = bc_u_at(u, gy, gx);
            sV[wy * 39 + wx] = bc_v_at(v, gy, gx);
        }
    }
    __syncthreads();

    // ---- phase A: predictor on 36x36 window ----
    if (!edge) {
        // 216 strips of 6 (36 rows x 6 strips) — ONE balanced pass
        if (t < 216) {
            int ay = t / 6, ax0 = (t - (t / 6) * 6) * 6;
            int base = ay * 39 + ax0;
            float b0[8], b1[8], b2[8];
            float d3u[6], x3u[6], y3u[6], uc6[6];
            STRIP6_LOAD(sU, base, 39)
#pragma unroll
            for (int k = 0; k < 6; ++k) {
                uc6[k] = b1[k+1];
                d3u[k] = strip_d3(b0, b1, b2, k);
                x3u[k] = strip_x3(b0, b1, b2, k);
                y3u[k] = strip_y3(b0, b1, b2, k);
            }
            float d3v[6], x3v[6], y3v[6], vc6[6];
            STRIP6_LOAD(sV, base, 39)
#pragma unroll
            for (int k = 0; k < 6; ++k) {
                vc6[k] = b1[k+1];
                d3v[k] = strip_d3(b0, b1, b2, k);
                x3v[k] = strip_x3(b0, b1, b2, k);
                y3v[k] = strip_y3(b0, b1, b2, k);
            }
            float gx6[6], gy6[6];
            STRIP6_LOAD(sP, base, 39)
#pragma unroll
            for (int k = 0; k < 6; ++k) {
                gx6[k] = strip_x3(b0, b1, b2, k) * DT;
                gy6[k] = strip_y3(b0, b1, b2, k) * DT;
            }
#pragma unroll
            for (int k = 0; k < 6; ++k) {
                int gy = y0 - 2 + ay, gx = x0 - 2 + ax0 + k;
                float dampv = 1.0f / (1.0f + DT * sigma[gy * GNX + gx]);
                float buv = (uc6[k] + 0.5f * (NUc * d3u[k] * DT - uc6[k] * x3u[k] * DT - vc6[k] * y3u[k] * DT) - gx6[k]) * dampv;
                float bvv = (vc6[k] + 0.5f * (NUc * d3v[k] * DT - uc6[k] * x3v[k] * DT - vc6[k] * y3v[k] * DT) - gy6[k]) * dampv;
                sBu[ay * 37 + ax0 + k] = buv;
                sBv[ay * 37 + ax0 + k] = bvv;
            }
        }
    } else {
        for (int i = t; i < 1296; i += 256) {
            int ay = i / 36, ax = i - ay * 36;
            int gy = y0 - 2 + ay, gx = x0 - 2 + ax;
            float un[3][3], vn[3][3], pn[3][3];
#pragma unroll
            for (int dy = 0; dy < 3; ++dy)
#pragma unroll
                for (int dx = 0; dx < 3; ++dx) {
                    int li = (ay + dy) * 39 + ax + dx;
                    un[dy][dx] = sU[li]; vn[dy][dx] = sV[li]; pn[dy][dx] = sP[li];
                }
            float buv, bvv;
            bool valid = (gy >= 0 && gy < GNY && gx >= 0 && gx < GNX);
            if (valid) {
                float dampv = 1.0f / (1.0f + DT * sigma[gy * GNX + gx]);
                float gxp = conv_x3(pn) * DT, gyp = conv_y3(pn) * DT;
                float uc = un[1][1], vc = vn[1][1];
                buv = (uc + 0.5f * (NUc * conv_d3(un) * DT - uc * conv_x3(un) * DT - vc * conv_y3(un) * DT) - gxp) * dampv;
                bvv = (vc + 0.5f * (NUc * conv_d3(vn) * DT - uc * conv_x3(vn) * DT - vc * conv_y3(vn) * DT) - gyp) * dampv;
            } else if (gy < 0 || gy >= GNY || gx < 0) {
                buv = 1.0f; bvv = 0.0f;
            } else {
                buv = 0.0f; bvv = 0.0f;
            }
            sBu[ay * 37 + ax] = buv;
            sBv[ay * 37 + ax] = bvv;
        }
    }
    __syncthreads();

    // ---- phase B: corrector on 34x34 window ----
    float ucS[6], vcS[6];          // strip preload (interior, 204 strips)
    float ucA[5], vcA[5];          // per-point preload (edge)
    if (!edge) {
        if (t < 204) {
            int cy = t / 6, cx0 = (t - (t / 6) * 6) * 6;
#pragma unroll
            for (int k = 0; k < 6; ++k) {
                if (cx0 + k < 34) {
                    int li = (cy + 2) * 39 + cx0 + 2 + k;
                    ucS[k] = sU[li]; vcS[k] = sV[li];
                }
            }
        }
    } else {
        int np = 0;
        for (int i = t; i < 1156; i += 256, ++np) {
            int cy = i / 34, cx = i - cy * 34;
            int li = (cy + 2) * 39 + cx + 2;
            ucA[np] = sU[li]; vcA[np] = sV[li];
        }
    }
    __syncthreads();
    if (!edge) {
        if (t < 204) {
            int cy = t / 6, cx0 = (t - (t / 6) * 6) * 6;
            int baseB = cy * 37 + cx0;
            int baseP = (cy + 1) * 39 + cx0 + 1;
            float b0[8], b1[8], b2[8];
            float d3bu[6], x3bu[6], y3bu[6], buc6[6];
            STRIP6_LOAD(sBu, baseB, 37)
#pragma unroll
            for (int k = 0; k < 6; ++k) {
                buc6[k] = b1[k+1];
                d3bu[k] = strip_d3(b0, b1, b2, k);
                x3bu[k] = strip_x3(b0, b1, b2, k);
                y3bu[k] = strip_y3(b0, b1, b2, k);
            }
            float d3bv[6], x3bv[6], y3bv[6], bvc6[6];
            STRIP6_LOAD(sBv, baseB, 37)
#pragma unroll
            for (int k = 0; k < 6; ++k) {
                bvc6[k] = b1[k+1];
                d3bv[k] = strip_d3(b0, b1, b2, k);
                x3bv[k] = strip_x3(b0, b1, b2, k);
                y3bv[k] = strip_y3(b0, b1, b2, k);
            }
            float gx6[6], gy6[6];
            STRIP6_LOAD(sP, baseP, 39)
#pragma unroll
            for (int k = 0; k < 6; ++k) {
                gx6[k] = strip_x3(b0, b1, b2, k) * DT;
                gy6[k] = strip_y3(b0, b1, b2, k) * DT;
            }
#pragma unroll
            for (int k = 0; k < 6; ++k) {
                if (cx0 + k < 34) {
                    int cx_ = cx0 + k;
                    int gyy = y0 - 1 + cy, gxx = x0 - 1 + cx_;
                    int idx = gyy * GNX + gxx;
                    float dampv = 1.0f / (1.0f + DT * sigma[idx]);
                    float u2_ = (ucS[k] + NUc * d3bu[k] * DT - buc6[k] * x3bu[k] * DT - bvc6[k] * y3bu[k] * DT - gx6[k]) * dampv;
                    float v2_ = (vcS[k] + NUc * d3bv[k] * DT - buc6[k] * x3bv[k] * DT - bvc6[k] * y3bv[k] * DT - gy6[k]) * dampv;
                    if (cy >= 1 && cy <= 32 && cx_ >= 1 && cx_ <= 32) {
                        u2g[idx] = u2_; v2g[idx] = v2_;
                    }
                    sU2[cy * 35 + cx_] = u2_;
                    sV2[cy * 35 + cx_] = v2_;
                }
            }
        }
    } else {
        int np = 0;
        for (int i = t; i < 1156; i += 256, ++np) {
            int cy = i / 34, cx = i - cy * 34;
            int gy = y0 - 1 + cy, gx = x0 - 1 + cx;
            float u2_ = 0.0f, v2_ = 0.0f;
            bool valid = (gy >= 0 && gy < GNY && gx >= 0 && gx < GNX);
            if (valid) {
                float bun[3][3], bvn[3][3], pn[3][3];
                if (!rightcol) {
#pragma unroll
                    for (int dy = 0; dy < 3; ++dy)
#pragma unroll
                        for (int dx = 0; dx < 3; ++dx) {
                            int li = (cy + dy) * 37 + cx + dx;
                            bun[dy][dx] = sBu[li]; bvn[dy][dx] = sBv[li];
                            pn[dy][dx] = sP[(cy + dy + 1) * 39 + cx + dx + 1];
                        }
                } else {
#pragma unroll
                    for (int dy = 0; dy < 3; ++dy)
#pragma unroll
                        for (int dx = 0; dx < 3; ++dx) {
                            int yy = gy + dy - 1, xx = gx + dx - 1;
                            pn[dy][dx] = sP[(cy + dy + 1) * 39 + cx + dx + 1];
                            if (yy < 0 || yy >= GNY || xx < 0) { bun[dy][dx] = 1.0f; bvn[dy][dx] = 0.0f; }
                            else {
                                int cxx = (xx >= GNX) ? GNX - 1 : xx;
                                int li = (cy + dy) * 37 + (cxx - (x0 - 2));
                                bun[dy][dx] = sBu[li]; bvn[dy][dx] = sBv[li];
                            }
                        }
                }
                int idx = gy * GNX + gx;
                float gxp = conv_x3(pn) * DT, gyp = conv_y3(pn) * DT;
                float dampv = 1.0f / (1.0f + DT * sigma[idx]);
                float buc = bun[1][1], bvc = bvn[1][1];
                u2_ = (ucA[np] + NUc * conv_d3(bun) * DT - buc * conv_x3(bun) * DT - bvc * conv_y3(bun) * DT - gxp) * dampv;
                v2_ = (vcA[np] + NUc * conv_d3(bvn) * DT - buc * conv_x3(bvn) * DT - bvc * conv_y3(bvn) * DT - gyp) * dampv;
                if (cy >= 1 && cy <= 32 && cx >= 1 && cx <= 32) {
                    u2g[idx] = u2_; v2g[idx] = v2_;
                }
            } else if (gy < 0 || gy >= GNY || gx < 0) {
                u2_ = 1.0f; v2_ = 0.0f;
            }
            sU2[cy * 35 + cx] = u2_;
            sV2[cy * 35 + cx] = v2_;
        }
    }
    __syncthreads();

    // ---- phase C: b on tile + r0 = A p - b (256 strips of 4 = 1/thread) ----
    if (!rightcol) {
        int ty = t >> 3, tx0 = (t & 7) * 4;
        int baseU = ty * 35 + tx0;
        int baseP = (ty + 2) * 39 + tx0 + 2;
        float b0[6], b1[6], b2[6];
        float x3u[4];
        STRIP_LOAD(sU2, baseU, 35)
#pragma unroll
        for (int k = 0; k < 4; ++k) x3u[k] = strip_x3(b0, b1, b2, k);
        float y3v[4];
        STRIP_LOAD(sV2, baseU, 35)
#pragma unroll
        for (int k = 0; k < 4; ++k) y3v[k] = strip_y3(b0, b1, b2, k);
        float d3p[4];
        STRIP_LOAD(sP, baseP, 39)
#pragma unroll
        for (int k = 0; k < 4; ++k) d3p[k] = strip_d3(b0, b1, b2, k);
#pragma unroll
        for (int k = 0; k < 4; ++k) {
            float b_ = -(x3u[k] + y3v[k]) * (1.0f / DT);
            bg[(y0 + ty) * GNX + x0 + tx0 + k] = b_;
            s0[ty * 33 + tx0 + k] = d3p[k] - b_;
        }
    } else {
        for (int i = t; i < 1024; i += 256) {
            int ty = i >> 5, tx = i & 31;
            int gy = y0 + ty, gx = x0 + tx;
            float un[3][3], vn[3][3], pn[3][3];
#pragma unroll
            for (int dy = 0; dy < 3; ++dy)
#pragma unroll
                for (int dx = 0; dx < 3; ++dx) {
                    int yy = gy + dy - 1, xx = gx + dx - 1;
                    pn[dy][dx] = sP[(ty + dy + 2) * 39 + tx + dx + 2];
                    if (yy < 0 || yy >= GNY || xx < 0) { un[dy][dx] = 1.0f; vn[dy][dx] = 0.0f; }
                    else {
                        int cxx = (xx >= GNX) ? GNX - 1 : xx;
                        int li = (ty + dy) * 35 + (cxx - (x0 - 1));
                        un[dy][dx] = sU2[li]; vn[dy][dx] = sV2[li];
                    }
                }
            float b_ = -(conv_x3(un) + conv_y3(vn)) * (1.0f / DT);
            bg[gy * GNX + gx] = b_;
            s0[ty * 33 + tx] = conv_d3(pn) - b_;
        }
    }
    __syncthreads();

    // ---- restriction chain r0 -> r1..r5 ----
    { int qy = t >> 4, qx = t & 15;
      float vv = 0.25f * (s0[(2*qy)*33 + 2*qx] + s0[(2*qy)*33 + 2*qx + 1]
                        + s0[(2*qy+1)*33 + 2*qx] + s0[(2*qy+1)*33 + 2*qx + 1]);
      s1[qy*17 + qx] = vv;
      r1[(by*16 + qy)*1024 + bx*16 + qx] = vv; }
    __syncthreads();
    if (t < 64) { int qy = t >> 3, qx = t & 7;
      float vv = 0.25f * (s1[(2*qy)*17 + 2*qx] + s1[(2*qy)*17 + 2*qx + 1]
                        + s1[(2*qy+1)*17 + 2*qx] + s1[(2*qy+1)*17 + 2*qx + 1]);
      s2[qy*9 + qx] = vv;
      r2[(by*8 + qy)*512 + bx*8 + qx] = vv; }
    __syncthreads();
    if (t < 16) { int qy = t >> 2, qx = t & 3;
      float vv = 0.25f * (s2[(2*qy)*9 + 2*qx] + s2[(2*qy)*9 + 2*qx + 1]
                        + s2[(2*qy+1)*9 + 2*qx] + s2[(2*qy+1)*9 + 2*qx + 1]);
      s3[qy*5 + qx] = vv;
      r3[(by*4 + qy)*256 + bx*4 + qx] = vv; }
    __syncthreads();
    if (t < 4) { int qy = t >> 1, qx = t & 1;
      float vv = 0.25f * (s3[(2*qy)*5 + 2*qx] + s3[(2*qy)*5 + 2*qx + 1]
                        + s3[(2*qy+1)*5 + 2*qx] + s3[(2*qy+1)*5 + 2*qx + 1]);
      s4[qy*3 + qx] = vv;
      r4[(by*2 + qy)*128 + bx*2 + qx] = vv; }
    __syncthreads();
    if (t == 0)
        r5[by*64 + bx] = 0.25f * (s4[0] + s4[1] + s4[3] + s4[4]);
}

// ---- ONE fused MG iteration; balanced strips in 3b/resid/projection ----
__global__ __launch_bounds__(256) void k_mg(
        const float* __restrict__ p_src, const float* __restrict__ b,
        const float* __restrict__ r1, const float* __restrict__ r2,
        const float* __restrict__ r3, const float* __restrict__ r4,
        const float* __restrict__ r5,
        float* __restrict__ p_dst,
        float* __restrict__ o1, float* __restrict__ o2, float* __restrict__ o3,
        float* __restrict__ o4, float* __restrict__ o5,
        const float* __restrict__ sigma, float* __restrict__ u_io,
        float* __restrict__ v_io, int last) {
    __shared__ float scr[3958];   // +10 pad for masked strip loads
    __shared__ float w6v[9], w5v[9], w4v[16], w3v[36], w2v[100], w1v[324];
    float* s5  = scr;            // 32x64 = 2048
    float* s6  = scr + 2048;     // 512
    float* s7  = scr + 2560;     // 128
    float* s8  = scr + 2688;     // 32
    float* s9  = scr + 2720;     // 8
    float* s10 = scr + 2728;     // 2
    float* a9  = scr + 2730;     // 8
    float* a8  = scr + 2738;     // 32
    float* a7  = scr + 2770;     // 128
    float* sPp = scr;            // 36x36, stride 37 = 1332
    float* sPn = scr + 1332;     // 34x34, stride 35 = 1190
    float* s0  = scr + 2522;     // 1056
    float* s1  = scr + 3578;     // 272
    float* s2  = scr + 3850;     // 72
    float* s3  = scr + 3922;     // 20
    float* s4  = scr + 3942;     // 6

    int t = threadIdx.x;
    int bx, by;
    swizzle_bid(bx, by);
    int y0 = by * 32, x0 = bx * 32;
    bool interior = (bx >= 1 && bx <= 62 && by >= 1 && by <= 30);

    // phase 1: full restriction r5 -> r10, tiny full up levels a10->a7
    for (int i = t; i < 2048; i += 256) s5[i] = r5[i];
    __syncthreads();
    for (int i = t; i < 512; i += 256) {
        int y = i >> 5, x = i & 31;
        s6[i] = 0.25f * (s5[(2*y)*64 + 2*x] + s5[(2*y)*64 + 2*x + 1]
                       + s5[(2*y+1)*64 + 2*x] + s5[(2*y+1)*64 + 2*x + 1]);
    }
    __syncthreads();
    if (t < 128) { int y = t >> 4, x = t & 15;
        s7[t] = 0.25f * (s6[(2*y)*32 + 2*x] + s6[(2*y)*32 + 2*x + 1]
                       + s6[(2*y+1)*32 + 2*x] + s6[(2*y+1)*32 + 2*x + 1]); }
    __syncthreads();
    if (t < 32) { int y = t >> 3, x = t & 7;
        s8[t] = 0.25f * (s7[(2*y)*16 + 2*x] + s7[(2*y)*16 + 2*x + 1]
                       + s7[(2*y+1)*16 + 2*x] + s7[(2*y+1)*16 + 2*x + 1]); }
    __syncthreads();
    if (t < 8) { int y = t >> 2, x = t & 3;
        s9[t] = 0.25f * (s8[(2*y)*8 + 2*x] + s8[(2*y)*8 + 2*x + 1]
                       + s8[(2*y+1)*8 + 2*x] + s8[(2*y+1)*8 + 2*x + 1]); }
    __syncthreads();
    if (t < 2)
        s10[t] = 0.25f * (s9[2*t] + s9[2*t + 1] + s9[4 + 2*t] + s9[4 + 2*t + 1]);
    __syncthreads();

    auto upv = [&](auto pget, float rval, int H, int W, int y, int x) -> float {
        float m[3][3];
#pragma unroll
        for (int dy = 0; dy < 3; ++dy)
#pragma unroll
            for (int dx = 0; dx < 3; ++dx) {
                int yy = y + dy - 1, xx = x + dx - 1;
                m[dy][dx] = (yy >= 0 && yy < H && xx >= 0 && xx < W) ? pget(yy >> 1, xx >> 1) : 0.0f;
            }
        float conv = (m[0][0] + m[0][1] + m[0][2] + m[1][0] + m[1][2]
                      + m[2][0] + m[2][1] + m[2][2] - 8.0f * m[1][1]) * (1.0f / 3.0f);
        return m[1][1] - conv * INV_DIAG + rval * INV_DIAG;
    };

    if (t < 8) { int y = t >> 2, x = t & 3;
        a9[t] = upv([&](int py, int px) { return s10[py*2 + px] * INV_DIAG; },
                    s9[t], 2, 4, y, x); }
    __syncthreads();
    if (t < 32) { int y = t >> 3, x = t & 7;
        a8[t] = upv([&](int py, int px) { return a9[py*4 + px]; },
                    s8[t], 4, 8, y, x); }
    __syncthreads();
    if (t < 128) { int y = t >> 4, x = t & 15;
        a7[t] = upv([&](int py, int px) { return a8[py*8 + px]; },
                    s7[t], 8, 16, y, x); }
    __syncthreads();

    // phase 2: windowed up-sweep a6..a1
    int w6ylo = (by - 2) >> 1, w6xlo = (bx - 2) >> 1;
    int w5ylo = by - 1,        w5xlo = bx - 1;
    int w4ylo = 2*by - 1,      w4xlo = 2*bx - 1;
    int w3ylo = 4*by - 1,      w3xlo = 4*bx - 1;
    int w2ylo = 8*by - 1,      w2xlo = 8*bx - 1;
    int w1ylo = 16*by - 1,     w1xlo = 16*bx - 1;

    if (t < 9) { int gy = w6ylo + t/3, gx = w6xlo + t%3;
        w6v[t] = (gy >= 0 && gy < 16 && gx >= 0 && gx < 32)
            ? upv([&](int py, int px) { return a7[py*16 + px]; },
                  s6[gy*32 + gx], 16, 32, gy, gx) : 0.0f; }
    __syncthreads();
    if (t < 9) { int gy = w5ylo + t/3, gx = w5xlo + t%3;
        w5v[t] = (gy >= 0 && gy < 32 && gx >= 0 && gx < 64)
            ? upv([&](int py, int px) { return w6v[(py - w6ylo)*3 + (px - w6xlo)]; },
                  s5[gy*64 + gx], 32, 64, gy, gx) : 0.0f; }
    __syncthreads();
    if (t < 16) { int gy = w4ylo + t/4, gx = w4xlo + t%4;
        w4v[t] = (gy >= 0 && gy < 64 && gx >= 0 && gx < 128)
            ? upv([&](int py, int px) { return w5v[(py - w5ylo)*3 + (px - w5xlo)]; },
                  r4[gy*128 + gx], 64, 128, gy, gx) : 0.0f; }
    __syncthreads();
    if (t < 36) { int gy = w3ylo + t/6, gx = w3xlo + t%6;
        w3v[t] = (gy >= 0 && gy < 128 && gx >= 0 && gx < 256)
            ? upv([&](int py, int px) { return w4v[(py - w4ylo)*4 + (px - w4xlo)]; },
                  r3[gy*256 + gx], 128, 256, gy, gx) : 0.0f; }
    __syncthreads();
    if (t < 100) { int gy = w2ylo + t/10, gx = w2xlo + t%10;
        w2v[t] = (gy >= 0 && gy < 256 && gx >= 0 && gx < 512)
            ? upv([&](int py, int px) { return w3v[(py - w3ylo)*6 + (px - w3xlo)]; },
                  r2[gy*512 + gx], 256, 512, gy, gx) : 0.0f; }
    __syncthreads();
    for (int i = t; i < 324; i += 256) { int gy = w1ylo + i/18, gx = w1xlo + i%18;
        w1v[i] = (gy >= 0 && gy < 512 && gx >= 0 && gx < 1024)
            ? upv([&](int py, int px) { return w2v[(py - w2ylo)*10 + (px - w2xlo)]; },
                  r1[gy*1024 + gx], 512, 1024, gy, gx) : 0.0f; }
    __syncthreads();

    // phase 3a: sPp = bc_p-mapped p' on 36x36 window
    for (int i = t; i < 1296; i += 256) {
        int wy = i / 36, wx = i - wy * 36;
        int yy = y0 - 2 + wy, xx = x0 - 2 + wx;
        float v = 0.0f;
        if (xx < GNX) {
            int cy = min(max(yy, 0), GNY - 1);
            int cx = xx < 0 ? 0 : xx;
            v = p_src[cy*GNX + cx] - w1v[((cy >> 1) - w1ylo)*18 + ((cx >> 1) - w1xlo)];
        }
        sPp[wy*37 + wx] = v;
    }
    __syncthreads();
    // phase 3b: sPn = p_next on 34x34
    if (interior) {
        // 204 strips of 6 — ONE balanced pass
        if (t < 204) {
            int wy = t / 6, wx0 = (t - (t / 6) * 6) * 6;
            int base = wy * 37 + wx0;
            float b0[8], b1[8], b2[8];
            STRIP6_LOAD(sPp, base, 37)
#pragma unroll
            for (int k = 0; k < 6; ++k) {
                if (wx0 + k < 34) {
                    float c = b1[k+1];
                    float conv = strip_d3(b0, b1, b2, k);
                    float bvv = b[(y0 - 1 + wy) * GNX + (x0 - 1 + wx0 + k)];
                    sPn[wy * 35 + wx0 + k] = c - conv * INV_DIAG + bvv * INV_DIAG;
                }
            }
        }
    } else {
        for (int i = t; i < 1156; i += 256) {
            int wy = i / 34, wx = i - wy * 34;
            int yy = y0 - 1 + wy, xx = x0 - 1 + wx;
            float v = 0.0f;
            if (xx < GNX) {
                int cy = min(max(yy, 0), GNY - 1);
                int cx = xx < 0 ? 0 : xx;
                int rb = cy - y0 + 2, cb = cx - x0 + 2;
                float m[3][3];
#pragma unroll
                for (int dy = 0; dy < 3; ++dy)
#pragma unroll
                    for (int dx = 0; dx < 3; ++dx)
                        m[dy][dx] = sPp[(rb + dy - 1)*37 + (cb + dx - 1)];
                float conv = (m[0][0] + m[0][1] + m[0][2] + m[1][0] + m[1][2]
                              + m[2][0] + m[2][1] + m[2][2] - 8.0f*m[1][1]) * (1.0f / 3.0f);
                v = m[1][1] - conv * INV_DIAG + b[cy*GNX + cx] * INV_DIAG;
            }
            sPn[wy*35 + wx] = v;
        }
    }
    __syncthreads();
    // write own p tile
    for (int i = t; i < 1024; i += 256) {
        int ty = i >> 5, tx = i & 31;
        p_dst[(y0 + ty)*GNX + x0 + tx] = sPn[(ty + 1)*35 + (tx + 1)];
    }

    if (!last) {
        // next-iteration residual (256 strips of 4 = 1/thread) + restriction
        {
            int ty = t >> 3, tx0 = (t & 7) * 4;
            int base = ty * 35 + tx0;
            float b0[6], b1[6], b2[6];
            STRIP_LOAD(sPn, base, 35)
#pragma unroll
            for (int k = 0; k < 4; ++k) {
                float d3 = strip_d3(b0, b1, b2, k);
                s0[ty * 33 + tx0 + k] = d3 - b[(y0 + ty) * GNX + x0 + tx0 + k];
            }
        }
        __syncthreads();
        { int qy = t >> 4, qx = t & 15;
          float v = 0.25f * (s0[(2*qy)*33 + 2*qx] + s0[(2*qy)*33 + 2*qx + 1]
                           + s0[(2*qy+1)*33 + 2*qx] + s0[(2*qy+1)*33 + 2*qx + 1]);
          s1[qy*17 + qx] = v;
          o1[(by*16 + qy)*1024 + bx*16 + qx] = v; }
        __syncthreads();
        if (t < 64) { int qy = t >> 3, qx = t & 7;
          float v = 0.25f * (s1[(2*qy)*17 + 2*qx] + s1[(2*qy)*17 + 2*qx + 1]
                           + s1[(2*qy+1)*17 + 2*qx] + s1[(2*qy+1)*17 + 2*qx + 1]);
          s2[qy*9 + qx] = v;
          o2[(by*8 + qy)*512 + bx*8 + qx] = v; }
        __syncthreads();
        if (t < 16) { int qy = t >> 2, qx = t & 3;
          float v = 0.25f * (s2[(2*qy)*9 + 2*qx] + s2[(2*qy)*9 + 2*qx + 1]
                           + s2[(2*qy+1)*9 + 2*qx] + s2[(2*qy+1)*9 + 2*qx + 1]);
          s3[qy*5 + qx] = v;
          o3[(by*4 + qy)*256 + bx*4 + qx] = v; }
        __syncthreads();
        if (t < 4) { int qy = t >> 1, qx = t & 1;
          float v = 0.25f * (s3[(2*qy)*5 + 2*qx] + s3[(2*qy)*5 + 2*qx + 1]
                           + s3[(2*qy+1)*5 + 2*qx] + s3[(2*qy+1)*5 + 2*qx + 1]);
          s4[qy*3 + qx] = v;
          o4[(by*2 + qy)*128 + bx*2 + qx] = v; }
        __syncthreads();
        if (t == 0)
            o5[by*64 + bx] = 0.25f * (s4[0] + s4[1] + s4[3] + s4[4]);
    } else {
        // fused projection (256 strips of 4 = 1/thread)
        int ty = t >> 3, tx0 = (t & 7) * 4;
        int base = ty * 35 + tx0;
        float b0[6], b1[6], b2[6];
        float x3p[4], y3p[4];
        STRIP_LOAD(sPn, base, 35)
#pragma unroll
        for (int k = 0; k < 4; ++k) {
            x3p[k] = strip_x3(b0, b1, b2, k);
            y3p[k] = strip_y3(b0, b1, b2, k);
        }
#pragma unroll
        for (int k = 0; k < 4; ++k) {
            int idx = (y0 + ty) * GNX + x0 + tx0 + k;
            float damp = 1.0f / (1.0f + DT * sigma[idx]);
            u_io[idx] = (u_io[idx] - x3p[k] * DT) * damp;
            v_io[idx] = (v_io[idx] - y3p[k] * DT) * damp;
        }
    }
}

extern "C" void kernel_launch(void* const* d_in, const int* in_sizes, int n_in,
                              void* d_out, int out_size, void* d_ws, size_t ws_size,
                              hipStream_t stream) {
    (void)in_sizes; (void)n_in; (void)out_size; (void)ws_size;
    const float* u_in  = (const float*)d_in[0];
    const float* v_in  = (const float*)d_in[1];
    const float* p_in  = (const float*)d_in[2];
    const float* sigma = (const float*)d_in[3];

    float* out_u = (float*)d_out;
    float* out_v = out_u + GNPTS;
    float* out_p = out_u + 2 * (size_t)GNPTS;

    float* ws   = (float*)d_ws;
    float* b    = ws;
    float* p_ws = b + (size_t)GNPTS;
    float* base = p_ws + (size_t)GNPTS;
    float* A_[5], * B_[5];
    size_t lsz[5] = {524288, 131072, 32768, 8192, 2048};
    float* cur = base;
    for (int l = 0; l < 5; ++l) { A_[l] = cur; cur += lsz[l]; }
    for (int l = 0; l < 5; ++l) { B_[l] = cur; cur += lsz[l]; }

    dim3 grdT(GNX / 32, GNY / 32), blkT(256);

    k_front<<<grdT, blkT, 0, stream>>>(u_in, v_in, p_in, sigma,
                                       out_u, out_v, b,
                                       A_[0], A_[1], A_[2], A_[3], A_[4]);

    const float* p_cur = p_in;
    float* p_bufs[2] = { out_p, p_ws };   // it0->out_p, it1->p_ws, ..., it4->out_p
    for (int it = 0; it < 5; ++it) {
        float** rp = (it % 2 == 0) ? A_ : B_;
        float** wp = (it % 2 == 0) ? B_ : A_;
        float* p_next = p_bufs[it % 2];
        int last = (it == 4) ? 1 : 0;
        k_mg<<<grdT, blkT, 0, stream>>>(p_cur, b,
                                        rp[0], rp[1], rp[2], rp[3], rp[4],
                                        p_next,
                                        wp[0], wp[1], wp[2], wp[3], wp[4],
                                        sigma, out_u, out_v, last);
        p_cur = p_next;
    }
}

// Round 14
// 194.069 us; speedup vs baseline: 1.2927x; 1.0050x over previous
//
#include <hip/hip_runtime.h>
#include <cstdint>

#define GNY 1024
#define GNX 2048
#define GNPTS (GNY * GNX)

namespace {
constexpr float DT = 0.1f;
constexpr float NUc = 0.01f;
constexpr float INV_DIAG = -0.375f;   // 1/DIAG, DIAG = -8/(3*dx^2) = -8/3
}

// XCD-aware swizzle: give XCD k a contiguous 4-row band (L2 halo locality).
__device__ __forceinline__ void swizzle_bid(int& bx, int& by) {
    int n = blockIdx.y * 64 + blockIdx.x;
    int i = n >> 3;
    bx = i & 63;
    by = ((n & 7) << 2) | (i >> 6);
}

// ---- boundary-condition index maps (verified against JAX .at[].set order) ----
__device__ __forceinline__ float bc_u_at(const float* __restrict__ f, int y, int x) {
    if (y < 0 || y >= GNY || x < 0) return 1.0f;
    if (x >= GNX) x = GNX - 1;
    return f[y * GNX + x];
}
__device__ __forceinline__ float bc_v_at(const float* __restrict__ f, int y, int x) {
    if (y < 0 || y >= GNY || x < 0) return 0.0f;
    if (x >= GNX) x = GNX - 1;
    return f[y * GNX + x];
}
__device__ __forceinline__ float bc_p_at(const float* __restrict__ f, int y, int x) {
    if (x >= GNX) return 0.0f;          // right ghost = 0 (dominates corners)
    if (x < 0) x = 0;
    y = min(max(y, 0), GNY - 1);
    return f[y * GNX + x];
}

// ---- stencils (cross-correlation, m[dy][dx] = f(y+dy-1, x+dx-1)) ----
__device__ __forceinline__ float conv_x3(const float m[3][3]) {
    return ((m[0][2] - m[0][0]) + 4.0f * (m[1][2] - m[1][0]) + (m[2][2] - m[2][0])) * (1.0f / 12.0f);
}
__device__ __forceinline__ float conv_y3(const float m[3][3]) {
    return ((m[2][0] - m[0][0]) + 4.0f * (m[2][1] - m[0][1]) + (m[2][2] - m[0][2])) * (1.0f / 12.0f);
}
__device__ __forceinline__ float conv_d3(const float m[3][3]) {
    return (m[0][0] + m[0][1] + m[0][2] + m[1][0] + m[1][2] + m[2][0] + m[2][1] + m[2][2]
            - 8.0f * m[1][1]) * (1.0f / 3.0f);
}

// strip helpers: b0/b1/b2 are 3 rows x (W+2) cols; k indexes the output
__device__ __forceinline__ float strip_d3(const float* b0, const float* b1, const float* b2, int k) {
    float cs0 = b0[k] + b1[k] + b2[k];
    float cs1 = b0[k+1] + b1[k+1] + b2[k+1];
    float cs2 = b0[k+2] + b1[k+2] + b2[k+2];
    return (cs0 + cs1 + cs2 - 9.0f * b1[k+1]) * (1.0f / 3.0f);
}
__device__ __forceinline__ float strip_x3(const float* b0, const float* b1, const float* b2, int k) {
    return ((b0[k+2] + 4.0f*b1[k+2] + b2[k+2]) - (b0[k] + 4.0f*b1[k] + b2[k])) * (1.0f / 12.0f);
}
__device__ __forceinline__ float strip_y3(const float* b0, const float* b1, const float* b2, int k) {
    return ((b2[k] - b0[k]) + 4.0f*(b2[k+1] - b0[k+1]) + (b2[k+2] - b0[k+2])) * (1.0f / 12.0f);
}
#define STRIP_LOAD(arr, base, stride) \
    { _Pragma("unroll") for (int j = 0; j < 6; ++j) { \
        b0[j] = arr[(base) + j]; b1[j] = arr[(base) + (stride) + j]; b2[j] = arr[(base) + 2*(stride) + j]; } }
#define STRIP6_LOAD(arr, base, stride) \
    { _Pragma("unroll") for (int j = 0; j < 8; ++j) { \
        b0[j] = arr[(base) + j]; b1[j] = arr[(base) + (stride) + j]; b2[j] = arr[(base) + 2*(stride) + j]; } }

// ---- FUSED front-end; float4 staging + balanced 6-wide strips ----
__global__ __launch_bounds__(256) void k_front(
        const float* __restrict__ u, const float* __restrict__ v,
        const float* __restrict__ p, const float* __restrict__ sigma,
        float* __restrict__ u2g, float* __restrict__ v2g, float* __restrict__ bg,
        float* __restrict__ r1, float* __restrict__ r2, float* __restrict__ r3,
        float* __restrict__ r4, float* __restrict__ r5) {
    __shared__ float scrF[7120];      // +10 pad: masked 8-wide strip loads stay in-bounds
    float* sP    = scrF;              // 38x38 stride 39 (1482), origin (y0-3,x0-3)
    float* sU    = scrF + 1482;
    float* sV    = scrF + 2964;
    float* sU2   = scrF + 1482;       // overlay, 34x35 (1190), origin (y0-1,x0-1)
    float* sV2   = scrF + 2672;
    float* sBu   = scrF + 4446;       // 36x37 (1332), origin (y0-2,x0-2)
    float* sBv   = scrF + 5778;
    float* s0    = scrF + 4446;       // overlay: 32x33 (1056)
    float* s1    = scrF + 5502;       // 16x17 (272)
    float* s2    = scrF + 5774;       // 8x9 (72)
    float* s3    = scrF + 5846;       // 4x5 (20)
    float* s4    = scrF + 5866;       // 2x3 (6)

    int t = threadIdx.x;
    int bx, by;
    swizzle_bid(bx, by);
    int y0 = by * 32, x0 = bx * 32;
    bool edge = !(bx >= 1 && bx <= 62 && by >= 1 && by <= 30);
    bool rightcol = (bx == 63);

    // ---- staging: bc-mapped u/v/p on 38x38 ----
    if (!edge) {
        // float4 path: 10 aligned quads/row cover window cols [-1, 38]
        for (int i = t; i < 380; i += 256) {
            int row = i / 10, q = 1 + (i - (i / 10) * 10);
            int gy = y0 - 3 + row;
            int c0 = x0 - 8 + 4 * q;                    // 16B-aligned
            size_t g4 = ((size_t)(gy * GNX + c0)) >> 2;
            float4 wp = ((const float4*)p)[g4];
            float4 wu = ((const float4*)u)[g4];
            float4 wv = ((const float4*)v)[g4];
            int wxb = 4 * q - 5;                        // window col of .x
#pragma unroll
            for (int j = 0; j < 4; ++j) {
                int wx = wxb + j;
                if (wx >= 0 && wx < 38) {
                    sP[row * 39 + wx] = ((const float*)&wp)[j];
                    sU[row * 39 + wx] = ((const float*)&wu)[j];
                    sV[row * 39 + wx] = ((const float*)&wv)[j];
                }
            }
        }
    } else {
        for (int i = t; i < 1444; i += 256) {
            int wy = i / 38, wx = i - wy * 38;
            int gy = y0 - 3 + wy, gx = x0 - 3 + wx;
            sP[wy * 39 + wx] = bc_p_at(p, gy, gx);
            sU[wy * 39 + wx] = bc_u_at(u, gy, gx);
            sV[wy * 39 + wx] = bc_v_at(v, gy, gx);
        }
    }
    __syncthreads();

    // ---- phase A: predictor on 36x36 window ----
    if (!edge) {
        if (t < 216) {
            int ay = t / 6, ax0 = (t - (t / 6) * 6) * 6;
            int base = ay * 39 + ax0;
            float b0[8], b1[8], b2[8];
            float d3u[6], x3u[6], y3u[6], uc6[6];
            STRIP6_LOAD(sU, base, 39)
#pragma unroll
            for (int k = 0; k < 6; ++k) {
                uc6[k] = b1[k+1];
                d3u[k] = strip_d3(b0, b1, b2, k);
                x3u[k] = strip_x3(b0, b1, b2, k);
                y3u[k] = strip_y3(b0, b1, b2, k);
            }
            float d3v[6], x3v[6], y3v[6], vc6[6];
            STRIP6_LOAD(sV, base, 39)
#pragma unroll
            for (int k = 0; k < 6; ++k) {
                vc6[k] = b1[k+1];
                d3v[k] = strip_d3(b0, b1, b2, k);
                x3v[k] = strip_x3(b0, b1, b2, k);
                y3v[k] = strip_y3(b0, b1, b2, k);
            }
            float gx6[6], gy6[6];
            STRIP6_LOAD(sP, base, 39)
#pragma unroll
            for (int k = 0; k < 6; ++k) {
                gx6[k] = strip_x3(b0, b1, b2, k) * DT;
                gy6[k] = strip_y3(b0, b1, b2, k) * DT;
            }
#pragma unroll
            for (int k = 0; k < 6; ++k) {
                int gy = y0 - 2 + ay, gx = x0 - 2 + ax0 + k;
                float dampv = 1.0f / (1.0f + DT * sigma[gy * GNX + gx]);
                float buv = (uc6[k] + 0.5f * (NUc * d3u[k] * DT - uc6[k] * x3u[k] * DT - vc6[k] * y3u[k] * DT) - gx6[k]) * dampv;
                float bvv = (vc6[k] + 0.5f * (NUc * d3v[k] * DT - uc6[k] * x3v[k] * DT - vc6[k] * y3v[k] * DT) - gy6[k]) * dampv;
                sBu[ay * 37 + ax0 + k] = buv;
                sBv[ay * 37 + ax0 + k] = bvv;
            }
        }
    } else {
        for (int i = t; i < 1296; i += 256) {
            int ay = i / 36, ax = i - ay * 36;
            int gy = y0 - 2 + ay, gx = x0 - 2 + ax;
            float un[3][3], vn[3][3], pn[3][3];
#pragma unroll
            for (int dy = 0; dy < 3; ++dy)
#pragma unroll
                for (int dx = 0; dx < 3; ++dx) {
                    int li = (ay + dy) * 39 + ax + dx;
                    un[dy][dx] = sU[li]; vn[dy][dx] = sV[li]; pn[dy][dx] = sP[li];
                }
            float buv, bvv;
            bool valid = (gy >= 0 && gy < GNY && gx >= 0 && gx < GNX);
            if (valid) {
                float dampv = 1.0f / (1.0f + DT * sigma[gy * GNX + gx]);
                float gxp = conv_x3(pn) * DT, gyp = conv_y3(pn) * DT;
                float uc = un[1][1], vc = vn[1][1];
                buv = (uc + 0.5f * (NUc * conv_d3(un) * DT - uc * conv_x3(un) * DT - vc * conv_y3(un) * DT) - gxp) * dampv;
                bvv = (vc + 0.5f * (NUc * conv_d3(vn) * DT - uc * conv_x3(vn) * DT - vc * conv_y3(vn) * DT) - gyp) * dampv;
            } else if (gy < 0 || gy >= GNY || gx < 0) {
                buv = 1.0f; bvv = 0.0f;
            } else {
                buv = 0.0f; bvv = 0.0f;
            }
            sBu[ay * 37 + ax] = buv;
            sBv[ay * 37 + ax] = bvv;
        }
    }
    __syncthreads();

    // ---- phase B: corrector on 34x34 window ----
    float ucS[6], vcS[6];
    float ucA[5], vcA[5];
    if (!edge) {
        if (t < 204) {
            int cy = t / 6, cx0 = (t - (t / 6) * 6) * 6;
#pragma unroll
            for (int k = 0; k < 6; ++k) {
                if (cx0 + k < 34) {
                    int li = (cy + 2) * 39 + cx0 + 2 + k;
                    ucS[k] = sU[li]; vcS[k] = sV[li];
                }
            }
        }
    } else {
        int np = 0;
        for (int i = t; i < 1156; i += 256, ++np) {
            int cy = i / 34, cx = i - cy * 34;
            int li = (cy + 2) * 39 + cx + 2;
            ucA[np] = sU[li]; vcA[np] = sV[li];
        }
    }
    __syncthreads();
    if (!edge) {
        if (t < 204) {
            int cy = t / 6, cx0 = (t - (t / 6) * 6) * 6;
            int baseB = cy * 37 + cx0;
            int baseP = (cy + 1) * 39 + cx0 + 1;
            float b0[8], b1[8], b2[8];
            float d3bu[6], x3bu[6], y3bu[6], buc6[6];
            STRIP6_LOAD(sBu, baseB, 37)
#pragma unroll
            for (int k = 0; k < 6; ++k) {
                buc6[k] = b1[k+1];
                d3bu[k] = strip_d3(b0, b1, b2, k);
                x3bu[k] = strip_x3(b0, b1, b2, k);
                y3bu[k] = strip_y3(b0, b1, b2, k);
            }
            float d3bv[6], x3bv[6], y3bv[6], bvc6[6];
            STRIP6_LOAD(sBv, baseB, 37)
#pragma unroll
            for (int k = 0; k < 6; ++k) {
                bvc6[k] = b1[k+1];
                d3bv[k] = strip_d3(b0, b1, b2, k);
                x3bv[k] = strip_x3(b0, b1, b2, k);
                y3bv[k] = strip_y3(b0, b1, b2, k);
            }
            float gx6[6], gy6[6];
            STRIP6_LOAD(sP, baseP, 39)
#pragma unroll
            for (int k = 0; k < 6; ++k) {
                gx6[k] = strip_x3(b0, b1, b2, k) * DT;
                gy6[k] = strip_y3(b0, b1, b2, k) * DT;
            }
#pragma unroll
            for (int k = 0; k < 6; ++k) {
                if (cx0 + k < 34) {
                    int cx_ = cx0 + k;
                    int gyy = y0 - 1 + cy, gxx = x0 - 1 + cx_;
                    int idx = gyy * GNX + gxx;
                    float dampv = 1.0f / (1.0f + DT * sigma[idx]);
                    float u2_ = (ucS[k] + NUc * d3bu[k] * DT - buc6[k] * x3bu[k] * DT - bvc6[k] * y3bu[k] * DT - gx6[k]) * dampv;
                    float v2_ = (vcS[k] + NUc * d3bv[k] * DT - buc6[k] * x3bv[k] * DT - bvc6[k] * y3bv[k] * DT - gy6[k]) * dampv;
                    if (cy >= 1 && cy <= 32 && cx_ >= 1 && cx_ <= 32) {
                        u2g[idx] = u2_; v2g[idx] = v2_;
                    }
                    sU2[cy * 35 + cx_] = u2_;
                    sV2[cy * 35 + cx_] = v2_;
                }
            }
        }
    } else {
        int np = 0;
        for (int i = t; i < 1156; i += 256, ++np) {
            int cy = i / 34, cx = i - cy * 34;
            int gy = y0 - 1 + cy, gx = x0 - 1 + cx;
            float u2_ = 0.0f, v2_ = 0.0f;
            bool valid = (gy >= 0 && gy < GNY && gx >= 0 && gx < GNX);
            if (valid) {
                float bun[3][3], bvn[3][3], pn[3][3];
                if (!rightcol) {
#pragma unroll
                    for (int dy = 0; dy < 3; ++dy)
#pragma unroll
                        for (int dx = 0; dx < 3; ++dx) {
                            int li = (cy + dy) * 37 + cx + dx;
                            bun[dy][dx] = sBu[li]; bvn[dy][dx] = sBv[li];
                            pn[dy][dx] = sP[(cy + dy + 1) * 39 + cx + dx + 1];
                        }
                } else {
#pragma unroll
                    for (int dy = 0; dy < 3; ++dy)
#pragma unroll
                        for (int dx = 0; dx < 3; ++dx) {
                            int yy = gy + dy - 1, xx = gx + dx - 1;
                            pn[dy][dx] = sP[(cy + dy + 1) * 39 + cx + dx + 1];
                            if (yy < 0 || yy >= GNY || xx < 0) { bun[dy][dx] = 1.0f; bvn[dy][dx] = 0.0f; }
                            else {
                                int cxx = (xx >= GNX) ? GNX - 1 : xx;
                                int li = (cy + dy) * 37 + (cxx - (x0 - 2));
                                bun[dy][dx] = sBu[li]; bvn[dy][dx] = sBv[li];
                            }
                        }
                }
                int idx = gy * GNX + gx;
                float gxp = conv_x3(pn) * DT, gyp = conv_y3(pn) * DT;
                float dampv = 1.0f / (1.0f + DT * sigma[idx]);
                float buc = bun[1][1], bvc = bvn[1][1];
                u2_ = (ucA[np] + NUc * conv_d3(bun) * DT - buc * conv_x3(bun) * DT - bvc * conv_y3(bun) * DT - gxp) * dampv;
                v2_ = (vcA[np] + NUc * conv_d3(bvn) * DT - buc * conv_x3(bvn) * DT - bvc * conv_y3(bvn) * DT - gyp) * dampv;
                if (cy >= 1 && cy <= 32 && cx <= 32 && cx >= 1) {
                    u2g[idx] = u2_; v2g[idx] = v2_;
                }
            } else if (gy < 0 || gy >= GNY || gx < 0) {
                u2_ = 1.0f; v2_ = 0.0f;
            }
            sU2[cy * 35 + cx] = u2_;
            sV2[cy * 35 + cx] = v2_;
        }
    }
    __syncthreads();

    // ---- phase C: b on tile + r0 = A p - b (256 strips of 4 = 1/thread) ----
    if (!rightcol) {
        int ty = t >> 3, tx0 = (t & 7) * 4;
        int baseU = ty * 35 + tx0;
        int baseP = (ty + 2) * 39 + tx0 + 2;
        float b0[6], b1[6], b2[6];
        float x3u[4];
        STRIP_LOAD(sU2, baseU, 35)
#pragma unroll
        for (int k = 0; k < 4; ++k) x3u[k] = strip_x3(b0, b1, b2, k);
        float y3v[4];
        STRIP_LOAD(sV2, baseU, 35)
#pragma unroll
        for (int k = 0; k < 4; ++k) y3v[k] = strip_y3(b0, b1, b2, k);
        float d3p[4];
        STRIP_LOAD(sP, baseP, 39)
#pragma unroll
        for (int k = 0; k < 4; ++k) d3p[k] = strip_d3(b0, b1, b2, k);
        float4 wb;
#pragma unroll
        for (int k = 0; k < 4; ++k) {
            float b_ = -(x3u[k] + y3v[k]) * (1.0f / DT);
            ((float*)&wb)[k] = b_;
            s0[ty * 33 + tx0 + k] = d3p[k] - b_;
        }
        ((float4*)bg)[((size_t)((y0 + ty) * GNX + x0 + tx0)) >> 2] = wb;
    } else {
        for (int i = t; i < 1024; i += 256) {
            int ty = i >> 5, tx = i & 31;
            int gy = y0 + ty, gx = x0 + tx;
            float un[3][3], vn[3][3], pn[3][3];
#pragma unroll
            for (int dy = 0; dy < 3; ++dy)
#pragma unroll
                for (int dx = 0; dx < 3; ++dx) {
                    int yy = gy + dy - 1, xx = gx + dx - 1;
                    pn[dy][dx] = sP[(ty + dy + 2) * 39 + tx + dx + 2];
                    if (yy < 0 || yy >= GNY || xx < 0) { un[dy][dx] = 1.0f; vn[dy][dx] = 0.0f; }
                    else {
                        int cxx = (xx >= GNX) ? GNX - 1 : xx;
                        int li = (ty + dy) * 35 + (cxx - (x0 - 1));
                        un[dy][dx] = sU2[li]; vn[dy][dx] = sV2[li];
                    }
                }
            float b_ = -(conv_x3(un) + conv_y3(vn)) * (1.0f / DT);
            bg[gy * GNX + gx] = b_;
            s0[ty * 33 + tx] = conv_d3(pn) - b_;
        }
    }
    __syncthreads();

    // ---- restriction chain r0 -> r1..r5 ----
    { int qy = t >> 4, qx = t & 15;
      float vv = 0.25f * (s0[(2*qy)*33 + 2*qx] + s0[(2*qy)*33 + 2*qx + 1]
                        + s0[(2*qy+1)*33 + 2*qx] + s0[(2*qy+1)*33 + 2*qx + 1]);
      s1[qy*17 + qx] = vv;
      r1[(by*16 + qy)*1024 + bx*16 + qx] = vv; }
    __syncthreads();
    if (t < 64) { int qy = t >> 3, qx = t & 7;
      float vv = 0.25f * (s1[(2*qy)*17 + 2*qx] + s1[(2*qy)*17 + 2*qx + 1]
                        + s1[(2*qy+1)*17 + 2*qx] + s1[(2*qy+1)*17 + 2*qx + 1]);
      s2[qy*9 + qx] = vv;
      r2[(by*8 + qy)*512 + bx*8 + qx] = vv; }
    __syncthreads();
    if (t < 16) { int qy = t >> 2, qx = t & 3;
      float vv = 0.25f * (s2[(2*qy)*9 + 2*qx] + s2[(2*qy)*9 + 2*qx + 1]
                        + s2[(2*qy+1)*9 + 2*qx] + s2[(2*qy+1)*9 + 2*qx + 1]);
      s3[qy*5 + qx] = vv;
      r3[(by*4 + qy)*256 + bx*4 + qx] = vv; }
    __syncthreads();
    if (t < 4) { int qy = t >> 1, qx = t & 1;
      float vv = 0.25f * (s3[(2*qy)*5 + 2*qx] + s3[(2*qy)*5 + 2*qx + 1]
                        + s3[(2*qy+1)*5 + 2*qx] + s3[(2*qy+1)*5 + 2*qx + 1]);
      s4[qy*3 + qx] = vv;
      r4[(by*2 + qy)*128 + bx*2 + qx] = vv; }
    __syncthreads();
    if (t == 0)
        r5[by*64 + bx] = 0.25f * (s4[0] + s4[1] + s4[3] + s4[4]);
}

// ---- ONE fused MG iteration; float4 r5 stage + p store, balanced strips ----
__global__ __launch_bounds__(256) void k_mg(
        const float* __restrict__ p_src, const float* __restrict__ b,
        const float* __restrict__ r1, const float* __restrict__ r2,
        const float* __restrict__ r3, const float* __restrict__ r4,
        const float* __restrict__ r5,
        float* __restrict__ p_dst,
        float* __restrict__ o1, float* __restrict__ o2, float* __restrict__ o3,
        float* __restrict__ o4, float* __restrict__ o5,
        const float* __restrict__ sigma, float* __restrict__ u_io,
        float* __restrict__ v_io, int last) {
    __shared__ float scr[3958];   // +10 pad for masked strip loads
    __shared__ float w6v[9], w5v[9], w4v[16], w3v[36], w2v[100], w1v[324];
    float* s5  = scr;            // 32x64 = 2048
    float* s6  = scr + 2048;     // 512
    float* s7  = scr + 2560;     // 128
    float* s8  = scr + 2688;     // 32
    float* s9  = scr + 2720;     // 8
    float* s10 = scr + 2728;     // 2
    float* a9  = scr + 2730;     // 8
    float* a8  = scr + 2738;     // 32
    float* a7  = scr + 2770;     // 128
    float* sPp = scr;            // 36x36, stride 37 = 1332
    float* sPn = scr + 1332;     // 34x34, stride 35 = 1190
    float* s0  = scr + 2522;     // 1056
    float* s1  = scr + 3578;     // 272
    float* s2  = scr + 3850;     // 72
    float* s3  = scr + 3922;     // 20
    float* s4  = scr + 3942;     // 6

    int t = threadIdx.x;
    int bx, by;
    swizzle_bid(bx, by);
    int y0 = by * 32, x0 = bx * 32;
    bool interior = (bx >= 1 && bx <= 62 && by >= 1 && by <= 30);

    // phase 1: stage r5 via float4 (2/thread), restriction chain, up a10->a7
#pragma unroll
    for (int k = 0; k < 2; ++k) {
        int i = t + 256 * k;
        float4 w = ((const float4*)r5)[i];
#pragma unroll
        for (int j = 0; j < 4; ++j) s5[4*i + j] = ((const float*)&w)[j];
    }
    __syncthreads();
    for (int i = t; i < 512; i += 256) {
        int y = i >> 5, x = i & 31;
        s6[i] = 0.25f * (s5[(2*y)*64 + 2*x] + s5[(2*y)*64 + 2*x + 1]
                       + s5[(2*y+1)*64 + 2*x] + s5[(2*y+1)*64 + 2*x + 1]);
    }
    __syncthreads();
    if (t < 128) { int y = t >> 4, x = t & 15;
        s7[t] = 0.25f * (s6[(2*y)*32 + 2*x] + s6[(2*y)*32 + 2*x + 1]
                       + s6[(2*y+1)*32 + 2*x] + s6[(2*y+1)*32 + 2*x + 1]); }
    __syncthreads();
    if (t < 32) { int y = t >> 3, x = t & 7;
        s8[t] = 0.25f * (s7[(2*y)*16 + 2*x] + s7[(2*y)*16 + 2*x + 1]
                       + s7[(2*y+1)*16 + 2*x] + s7[(2*y+1)*16 + 2*x + 1]); }
    __syncthreads();
    if (t < 8) { int y = t >> 2, x = t & 3;
        s9[t] = 0.25f * (s8[(2*y)*8 + 2*x] + s8[(2*y)*8 + 2*x + 1]
                       + s8[(2*y+1)*8 + 2*x] + s8[(2*y+1)*8 + 2*x + 1]); }
    __syncthreads();
    if (t < 2)
        s10[t] = 0.25f * (s9[2*t] + s9[2*t + 1] + s9[4 + 2*t] + s9[4 + 2*t + 1]);
    __syncthreads();

    auto upv = [&](auto pget, float rval, int H, int W, int y, int x) -> float {
        float m[3][3];
#pragma unroll
        for (int dy = 0; dy < 3; ++dy)
#pragma unroll
            for (int dx = 0; dx < 3; ++dx) {
                int yy = y + dy - 1, xx = x + dx - 1;
                m[dy][dx] = (yy >= 0 && yy < H && xx >= 0 && xx < W) ? pget(yy >> 1, xx >> 1) : 0.0f;
            }
        float conv = (m[0][0] + m[0][1] + m[0][2] + m[1][0] + m[1][2]
                      + m[2][0] + m[2][1] + m[2][2] - 8.0f * m[1][1]) * (1.0f / 3.0f);
        return m[1][1] - conv * INV_DIAG + rval * INV_DIAG;
    };

    if (t < 8) { int y = t >> 2, x = t & 3;
        a9[t] = upv([&](int py, int px) { return s10[py*2 + px] * INV_DIAG; },
                    s9[t], 2, 4, y, x); }
    __syncthreads();
    if (t < 32) { int y = t >> 3, x = t & 7;
        a8[t] = upv([&](int py, int px) { return a9[py*4 + px]; },
                    s8[t], 4, 8, y, x); }
    __syncthreads();
    if (t < 128) { int y = t >> 4, x = t & 15;
        a7[t] = upv([&](int py, int px) { return a8[py*8 + px]; },
                    s7[t], 8, 16, y, x); }
    __syncthreads();

    // phase 2: windowed up-sweep a6..a1
    int w6ylo = (by - 2) >> 1, w6xlo = (bx - 2) >> 1;
    int w5ylo = by - 1,        w5xlo = bx - 1;
    int w4ylo = 2*by - 1,      w4xlo = 2*bx - 1;
    int w3ylo = 4*by - 1,      w3xlo = 4*bx - 1;
    int w2ylo = 8*by - 1,      w2xlo = 8*bx - 1;
    int w1ylo = 16*by - 1,     w1xlo = 16*bx - 1;

    if (t < 9) { int gy = w6ylo + t/3, gx = w6xlo + t%3;
        w6v[t] = (gy >= 0 && gy < 16 && gx >= 0 && gx < 32)
            ? upv([&](int py, int px) { return a7[py*16 + px]; },
                  s6[gy*32 + gx], 16, 32, gy, gx) : 0.0f; }
    __syncthreads();
    if (t < 9) { int gy = w5ylo + t/3, gx = w5xlo + t%3;
        w5v[t] = (gy >= 0 && gy < 32 && gx >= 0 && gx < 64)
            ? upv([&](int py, int px) { return w6v[(py - w6ylo)*3 + (px - w6xlo)]; },
                  s5[gy*64 + gx], 32, 64, gy, gx) : 0.0f; }
    __syncthreads();
    if (t < 16) { int gy = w4ylo + t/4, gx = w4xlo + t%4;
        w4v[t] = (gy >= 0 && gy < 64 && gx >= 0 && gx < 128)
            ? upv([&](int py, int px) { return w5v[(py - w5ylo)*3 + (px - w5xlo)]; },
                  r4[gy*128 + gx], 64, 128, gy, gx) : 0.0f; }
    __syncthreads();
    if (t < 36) { int gy = w3ylo + t/6, gx = w3xlo + t%6;
        w3v[t] = (gy >= 0 && gy < 128 && gx >= 0 && gx < 256)
            ? upv([&](int py, int px) { return w4v[(py - w4ylo)*4 + (px - w4xlo)]; },
                  r3[gy*256 + gx], 128, 256, gy, gx) : 0.0f; }
    __syncthreads();
    if (t < 100) { int gy = w2ylo + t/10, gx = w2xlo + t%10;
        w2v[t] = (gy >= 0 && gy < 256 && gx >= 0 && gx < 512)
            ? upv([&](int py, int px) { return w3v[(py - w3ylo)*6 + (px - w3xlo)]; },
                  r2[gy*512 + gx], 256, 512, gy, gx) : 0.0f; }
    __syncthreads();
    for (int i = t; i < 324; i += 256) { int gy = w1ylo + i/18, gx = w1xlo + i%18;
        w1v[i] = (gy >= 0 && gy < 512 && gx >= 0 && gx < 1024)
            ? upv([&](int py, int px) { return w2v[(py - w2ylo)*10 + (px - w2xlo)]; },
                  r1[gy*1024 + gx], 512, 1024, gy, gx) : 0.0f; }
    __syncthreads();

    // phase 3a: sPp = bc_p-mapped p' on 36x36 window
    for (int i = t; i < 1296; i += 256) {
        int wy = i / 36, wx = i - wy * 36;
        int yy = y0 - 2 + wy, xx = x0 - 2 + wx;
        float v = 0.0f;
        if (xx < GNX) {
            int cy = min(max(yy, 0), GNY - 1);
            int cx = xx < 0 ? 0 : xx;
            v = p_src[cy*GNX + cx] - w1v[((cy >> 1) - w1ylo)*18 + ((cx >> 1) - w1xlo)];
        }
        sPp[wy*37 + wx] = v;
    }
    __syncthreads();
    // phase 3b: sPn = p_next on 34x34
    if (interior) {
        if (t < 204) {
            int wy = t / 6, wx0 = (t - (t / 6) * 6) * 6;
            int base = wy * 37 + wx0;
            float b0[8], b1[8], b2[8];
            STRIP6_LOAD(sPp, base, 37)
#pragma unroll
            for (int k = 0; k < 6; ++k) {
                if (wx0 + k < 34) {
                    float c = b1[k+1];
                    float conv = strip_d3(b0, b1, b2, k);
                    float bvv = b[(y0 - 1 + wy) * GNX + (x0 - 1 + wx0 + k)];
                    sPn[wy * 35 + wx0 + k] = c - conv * INV_DIAG + bvv * INV_DIAG;
                }
            }
        }
    } else {
        for (int i = t; i < 1156; i += 256) {
            int wy = i / 34, wx = i - wy * 34;
            int yy = y0 - 1 + wy, xx = x0 - 1 + wx;
            float v = 0.0f;
            if (xx < GNX) {
                int cy = min(max(yy, 0), GNY - 1);
                int cx = xx < 0 ? 0 : xx;
                int rb = cy - y0 + 2, cb = cx - x0 + 2;
                float m[3][3];
#pragma unroll
                for (int dy = 0; dy < 3; ++dy)
#pragma unroll
                    for (int dx = 0; dx < 3; ++dx)
                        m[dy][dx] = sPp[(rb + dy - 1)*37 + (cb + dx - 1)];
                float conv = (m[0][0] + m[0][1] + m[0][2] + m[1][0] + m[1][2]
                              + m[2][0] + m[2][1] + m[2][2] - 8.0f*m[1][1]) * (1.0f / 3.0f);
                v = m[1][1] - conv * INV_DIAG + b[cy*GNX + cx] * INV_DIAG;
            }
            sPn[wy*35 + wx] = v;
        }
    }
    __syncthreads();
    // write own p tile (float4, 1/thread)
    {
        int row = t >> 3, q = t & 7;
        float4 w;
#pragma unroll
        for (int j = 0; j < 4; ++j)
            ((float*)&w)[j] = sPn[(row + 1)*35 + q*4 + 1 + j];
        ((float4*)p_dst)[((size_t)((y0 + row)*GNX + x0 + q*4)) >> 2] = w;
    }

    if (!last) {
        // next-iteration residual (256 strips of 4 = 1/thread) + restriction
        {
            int ty = t >> 3, tx0 = (t & 7) * 4;
            int base = ty * 35 + tx0;
            float b0[6], b1[6], b2[6];
            STRIP_LOAD(sPn, base, 35)
#pragma unroll
            for (int k = 0; k < 4; ++k) {
                float d3 = strip_d3(b0, b1, b2, k);
                s0[ty * 33 + tx0 + k] = d3 - b[(y0 + ty) * GNX + x0 + tx0 + k];
            }
        }
        __syncthreads();
        { int qy = t >> 4, qx = t & 15;
          float v = 0.25f * (s0[(2*qy)*33 + 2*qx] + s0[(2*qy)*33 + 2*qx + 1]
                           + s0[(2*qy+1)*33 + 2*qx] + s0[(2*qy+1)*33 + 2*qx + 1]);
          s1[qy*17 + qx] = v;
          o1[(by*16 + qy)*1024 + bx*16 + qx] = v; }
        __syncthreads();
        if (t < 64) { int qy = t >> 3, qx = t & 7;
          float v = 0.25f * (s1[(2*qy)*17 + 2*qx] + s1[(2*qy)*17 + 2*qx + 1]
                           + s1[(2*qy+1)*17 + 2*qx] + s1[(2*qy+1)*17 + 2*qx + 1]);
          s2[qy*9 + qx] = v;
          o2[(by*8 + qy)*512 + bx*8 + qx] = v; }
        __syncthreads();
        if (t < 16) { int qy = t >> 2, qx = t & 3;
          float v = 0.25f * (s2[(2*qy)*9 + 2*qx] + s2[(2*qy)*9 + 2*qx + 1]
                           + s2[(2*qy+1)*9 + 2*qx] + s2[(2*qy+1)*9 + 2*qx + 1]);
          s3[qy*5 + qx] = v;
          o3[(by*4 + qy)*256 + bx*4 + qx] = v; }
        __syncthreads();
        if (t < 4) { int qy = t >> 1, qx = t & 1;
          float v = 0.25f * (s3[(2*qy)*5 + 2*qx] + s3[(2*qy)*5 + 2*qx + 1]
                           + s3[(2*qy+1)*5 + 2*qx] + s3[(2*qy+1)*5 + 2*qx + 1]);
          s4[qy*3 + qx] = v;
          o4[(by*2 + qy)*128 + bx*2 + qx] = v; }
        __syncthreads();
        if (t == 0)
            o5[by*64 + bx] = 0.25f * (s4[0] + s4[1] + s4[3] + s4[4]);
    } else {
        // fused projection (256 strips of 4 = 1/thread)
        int ty = t >> 3, tx0 = (t & 7) * 4;
        int base = ty * 35 + tx0;
        float b0[6], b1[6], b2[6];
        float x3p[4], y3p[4];
        STRIP_LOAD(sPn, base, 35)
#pragma unroll
        for (int k = 0; k < 4; ++k) {
            x3p[k] = strip_x3(b0, b1, b2, k);
            y3p[k] = strip_y3(b0, b1, b2, k);
        }
#pragma unroll
        for (int k = 0; k < 4; ++k) {
            int idx = (y0 + ty) * GNX + x0 + tx0 + k;
            float damp = 1.0f / (1.0f + DT * sigma[idx]);
            u_io[idx] = (u_io[idx] - x3p[k] * DT) * damp;
            v_io[idx] = (v_io[idx] - y3p[k] * DT) * damp;
        }
    }
}

extern "C" void kernel_launch(void* const* d_in, const int* in_sizes, int n_in,
                              void* d_out, int out_size, void* d_ws, size_t ws_size,
                              hipStream_t stream) {
    (void)in_sizes; (void)n_in; (void)out_size; (void)ws_size;
    const float* u_in  = (const float*)d_in[0];
    const float* v_in  = (const float*)d_in[1];
    const float* p_in  = (const float*)d_in[2];
    const float* sigma = (const float*)d_in[3];

    float* out_u = (float*)d_out;
    float* out_v = out_u + GNPTS;
    float* out_p = out_u + 2 * (size_t)GNPTS;

    float* ws   = (float*)d_ws;
    float* b    = ws;
    float* p_ws = b + (size_t)GNPTS;
    float* base = p_ws + (size_t)GNPTS;
    float* A_[5], * B_[5];
    size_t lsz[5] = {524288, 131072, 32768, 8192, 2048};
    float* cur = base;
    for (int l = 0; l < 5; ++l) { A_[l] = cur; cur += lsz[l]; }
    for (int l = 0; l < 5; ++l) { B_[l] = cur; cur += lsz[l]; }

    dim3 grdT(GNX / 32, GNY / 32), blkT(256);

    k_front<<<grdT, blkT, 0, stream>>>(u_in, v_in, p_in, sigma,
                                       out_u, out_v, b,
                                       A_[0], A_[1], A_[2], A_[3], A_[4]);

    const float* p_cur = p_in;
    float* p_bufs[2] = { out_p, p_ws };   // it0->out_p, it1->p_ws, ..., it4->out_p
    for (int it = 0; it < 5; ++it) {
        float** rp = (it % 2 == 0) ? A_ : B_;
        float** wp = (it % 2 == 0) ? B_ : A_;
        float* p_next = p_bufs[it % 2];
        int last = (it == 4) ? 1 : 0;
        k_mg<<<grdT, blkT, 0, stream>>>(p_cur, b,
                                        rp[0], rp[1], rp[2], rp[3], rp[4],
                                        p_next,
                                        wp[0], wp[1], wp[2], wp[3], wp[4],
                                        sigma, out_u, out_v, last);
        p_cur = p_next;
    }
}